// Round 9
// baseline (361.423 us; speedup 1.0000x reference)
//
#include <hip/hip_runtime.h>
#include <math.h>

#define KD 5
#define NN 60000
#define EE 360000
#define NP1 30000
#define EE2 180000
#define NP2 15000
#define GG 60

// conv2 bucketing (256-aligned buckets, one cell per 256-thread block)
#define PAD256 (EE2 + 25 * 256)         // 186400 worst-case padded total
#define NB2 ((PAD256 + 255) / 256)      // 729 blocks

// pool2/global-pool partials
#define PB2 120
#define CPB2 125   // ceil(NP2 / PB2)

// ---------- helpers ----------

__device__ __forceinline__ unsigned fkey(float f) {
    unsigned u = __float_as_uint(f);
    return (u & 0x80000000u) ? ~u : (u | 0x80000000u);
}
__device__ __forceinline__ float fkey_inv(unsigned k) {
    unsigned u = (k & 0x80000000u) ? (k ^ 0x80000000u) : ~k;
    return __uint_as_float(u);
}

__device__ __forceinline__ void spline_basis(float p0, float p1, int* idx, float* w) {
    float v0 = p0 * 4.0f, v1 = p1 * 4.0f;
    float fl0 = floorf(v0), fl1 = floorf(v1);
    int i0 = min(max((int)fl0, 0), KD - 1);
    int i1 = min(max((int)fl1, 0), KD - 1);
    float fr0 = v0 - fl0, fr1 = v1 - fl1;
    int c = 0;
#pragma unroll
    for (int s0 = 0; s0 < 2; ++s0) {
#pragma unroll
        for (int s1 = 0; s1 < 2; ++s1) {
            int ix = min(i0 + s0, KD - 1);
            int iy = min(i1 + s1, KD - 1);
            float w0 = s0 ? fr0 : 1.0f - fr0;
            float w1 = s1 ? fr1 : 1.0f - fr1;
            idx[c] = ix + KD * iy;
            w[c] = w0 * w1;
            ++c;
        }
    }
}

// cell + basis weights from RAW cartesian attr (applies the scale transform
// inline, bit-identical to attr2 = c/(2s)+0.5 then v = attr*4)
__device__ __forceinline__ void cell_basis(float c0, float c1, float s,
                                           int& cell, float4& w4) {
    float p0 = c0 / (2.0f * s) + 0.5f;
    float p1 = c1 / (2.0f * s) + 0.5f;
    float v0 = p0 * 4.0f, v1 = p1 * 4.0f;
    float fl0 = floorf(v0), fl1 = floorf(v1);
    int i0 = min(max((int)fl0, 0), KD - 1);
    int i1 = min(max((int)fl1, 0), KD - 1);
    float fr0 = v0 - fl0, fr1 = v1 - fl1;
    cell = i0 + 5 * i1;
    w4.x = (1.0f - fr0) * (1.0f - fr1);  // k=0 (s0=0,s1=0)
    w4.y = (1.0f - fr0) * fr1;           // k=1 (s0=0,s1=1)
    w4.z = fr0 * (1.0f - fr1);           // k=2 (s0=1,s1=0)
    w4.w = fr0 * fr1;                    // k=3 (s0=1,s1=1)
}

__device__ __forceinline__ float elu1(float v) {
    return v > 0.0f ? v : expm1f(v);
}

// ---------- conv1 ----------

__global__ void conv1_edge(const float* __restrict__ x, const float* __restrict__ ea,
                           const int* __restrict__ ei, const float* __restrict__ W1,
                           float* __restrict__ agg1, float* __restrict__ cnt1) {
    int gid = blockIdx.x * blockDim.x + threadIdx.x;
    if (gid >= EE * 32) return;
    int e = gid >> 5, f = gid & 31;
    int src = ei[e], dst = ei[EE + e];
    int idx[4]; float w[4];
    spline_basis(ea[2 * e], ea[2 * e + 1], idx, w);
    float coeff = 0.0f;
#pragma unroll
    for (int k = 0; k < 4; ++k) coeff += w[k] * W1[idx[k] * 32 + f];
    atomicAdd(&agg1[dst * 32 + f], x[src] * coeff);
    if (f == 0) atomicAdd(&cnt1[dst], 1.0f);
}

// ---------- conv1 finish + pool1 (fused: same geometry, h kept in-register) ----------

__global__ void conv1fin_pool1(const float* __restrict__ x, const float* __restrict__ root1,
                               const float* __restrict__ bias1, const float* __restrict__ cnt1,
                               const float* __restrict__ agg1, const float* __restrict__ pos,
                               const int* __restrict__ batch, const int* __restrict__ cl1,
                               unsigned* __restrict__ x1key, int* __restrict__ ccnt1,
                               float* __restrict__ pos1, int* __restrict__ batch1) {
    int gid = blockIdx.x * blockDim.x + threadIdx.x;
    if (gid >= NN * 32) return;
    int n = gid >> 5, f = gid & 31;
    float v = elu1(agg1[gid] / fmaxf(cnt1[n], 1.0f) + x[n] * root1[f] + bias1[f]);
    int c = cl1[n];
    atomicMax(&x1key[c * 32 + f], fkey(v));
    if (f == 0) {
        atomicAdd(&ccnt1[c], 1);
        atomicAdd(&pos1[c * 2], pos[n * 2]);
        atomicAdd(&pos1[c * 2 + 1], pos[n * 2 + 1]);
        atomicMax(&batch1[c], batch[n]);
    }
}

__global__ void pool1_fin(unsigned* __restrict__ x1key, const int* __restrict__ ccnt1,
                          float* __restrict__ pos1) {
    int gid = blockIdx.x * blockDim.x + threadIdx.x;
    if (gid >= NP1 * 32) return;
    int c = gid >> 5, f = gid & 31;
    int cnt = ccnt1[c];
    float v = cnt > 0 ? fkey_inv(x1key[gid]) : 0.0f;
    ((float*)x1key)[gid] = v;
    if (f < 2) pos1[c * 2 + f] = pos1[c * 2 + f] / fmaxf((float)cnt, 1.0f);
}

// ---------- cartesian (stores RAW cart; also counts cnt2 per dst) ----------

__global__ void cart_k(const float* __restrict__ pos1, const int* __restrict__ ei2,
                       float* __restrict__ cart, unsigned* __restrict__ scaleb,
                       float* __restrict__ cnt2) {
    int e = blockIdx.x * blockDim.x + threadIdx.x;
    float m = 0.0f;
    if (e < EE2) {
        int s = ei2[e], d = ei2[EE2 + e];
        float c0 = pos1[d * 2] - pos1[s * 2];
        float c1 = pos1[d * 2 + 1] - pos1[s * 2 + 1];
        cart[e * 2] = c0;
        cart[e * 2 + 1] = c1;
        m = fmaxf(fabsf(c0), fabsf(c1));
        atomicAdd(&cnt2[d], 1.0f);
    }
#pragma unroll
    for (int off = 32; off > 0; off >>= 1) m = fmaxf(m, __shfl_down(m, off));
    if ((threadIdx.x & 63) == 0) atomicMax(scaleb, __float_as_uint(m));
}

// ---------- conv2 bucketing by B-spline cell ----------

__global__ void bucket_count(const float* __restrict__ cart,
                             const unsigned* __restrict__ scaleb,
                             int* __restrict__ ccount) {
    __shared__ int lc[25];
    int t = threadIdx.x;
    if (t < 25) lc[t] = 0;
    __syncthreads();
    int e = blockIdx.x * blockDim.x + t;
    if (e < EE2) {
        float s = fmaxf(__uint_as_float(*scaleb), 1e-12f);
        int cell; float4 w4;
        cell_basis(cart[2 * e], cart[2 * e + 1], s, cell, w4);
        atomicAdd(&lc[cell], 1);
    }
    __syncthreads();
    if (t < 25 && lc[t] > 0) atomicAdd(&ccount[t], lc[t]);
}

__global__ void bucket_scan(const int* __restrict__ ccount, int* __restrict__ aoff,
                            int* __restrict__ gcursor) {
    if (blockIdx.x == 0 && threadIdx.x == 0) {
        int acc = 0;
        for (int c = 0; c < 25; ++c) {
            aoff[c] = acc;
            gcursor[c] = acc;
            acc += (ccount[c] + 255) & ~255;   // 256-align each bucket
        }
        aoff[25] = acc;
    }
}

__global__ void bucket_scatter(const float* __restrict__ cart,
                               const unsigned* __restrict__ scaleb,
                               const int* __restrict__ ei2,
                               int* __restrict__ gcursor,
                               int* __restrict__ bsrc, int* __restrict__ bdst,
                               float4* __restrict__ bw) {
    __shared__ int lc[25], lb[25];
    int t = threadIdx.x;
    if (t < 25) lc[t] = 0;
    __syncthreads();
    int e = blockIdx.x * blockDim.x + t;
    bool valid = e < EE2;
    int cell = 0, rank = 0;
    float4 w4 = make_float4(0.f, 0.f, 0.f, 0.f);
    if (valid) {
        float s = fmaxf(__uint_as_float(*scaleb), 1e-12f);
        cell_basis(cart[2 * e], cart[2 * e + 1], s, cell, w4);
        rank = atomicAdd(&lc[cell], 1);
    }
    __syncthreads();
    if (t < 25) lb[t] = lc[t] > 0 ? atomicAdd(&gcursor[t], lc[t]) : 0;
    __syncthreads();
    if (valid) {
        int pos = lb[cell] + rank;
        bsrc[pos] = ei2[e];
        bdst[pos] = ei2[EE2 + e];
        bw[pos] = w4;
    }
}

// ---------- conv2: one cell per block, weights in LDS, 4 edges in flight ----------
// Weight LDS layout (fi-quad transposed): float4 unit u = (k*8+g)*64 + fout
// holds W2[slot_k][g*4 .. g*4+3][fout]. Each ds_read_b128 is reused by the
// 4 in-flight edges -> LDS weight traffic / 4 = 1.47GB (~19us floor), FMA
// 1.47G MAC (~19us floor). No register-residency fight (acc/xq ~80 VGPR).

__global__ __launch_bounds__(256) void conv2_cell(const int* __restrict__ bsrc,
                                                  const int* __restrict__ bdst,
                                                  const float4* __restrict__ bw,
                                                  const int* __restrict__ aoff,
                                                  const float* __restrict__ x1,
                                                  const float* __restrict__ W2,
                                                  float* __restrict__ agg2) {
    __shared__ float wl[4 * 8 * 64 * 4];   // 32KB
    __shared__ int soff[26];
    const int t = threadIdx.x;
    if (t < 26) soff[t] = aoff[t];
    __syncthreads();
    const int base = blockIdx.x * 256;
    if (base >= soff[25]) return;          // uniform over block
    int cell = 0;
#pragma unroll
    for (int c = 1; c < 25; ++c) cell += (base >= soff[c]) ? 1 : 0;
    const int cx = cell % 5, cy = cell / 5;

    // stage this cell's 4-slot weight block (coalesced global read)
    for (int i = t; i < 8192; i += 256) {
        int s  = i >> 11;          // k slot index 0..3
        int fi = (i >> 6) & 31;
        int fo = i & 63;
        int slot = min(cx + (s >> 1), 4) + 5 * min(cy + (s & 1), 4);
        wl[(((s * 8 + (fi >> 2)) * 64) + fo) * 4 + (fi & 3)] = W2[slot * 2048 + fi * 64 + fo];
    }
    __syncthreads();

    const int lane = t & 63;
    const int wbase = base + (t >> 6) * 64;   // this wave's 64-edge segment
    const float4* wl4 = (const float4*)wl;

    for (int q = 0; q < 64; q += 4) {
        const int e0 = wbase + q;
        int srcs[4], dsts[4];
        float4 w4s[4];
#pragma unroll
        for (int e = 0; e < 4; ++e) {
            srcs[e] = bsrc[e0 + e];
            dsts[e] = bdst[e0 + e];
            w4s[e] = bw[e0 + e];
        }
        float acc[4][4] = {};   // [edge][k]
#pragma unroll
        for (int g = 0; g < 8; ++g) {
            float4 xq[4];
#pragma unroll
            for (int e = 0; e < 4; ++e)
                xq[e] = (srcs[e] >= 0) ? *(const float4*)(x1 + srcs[e] * 32 + g * 4)
                                       : make_float4(0.f, 0.f, 0.f, 0.f);
#pragma unroll
            for (int k = 0; k < 4; ++k) {
                float4 wv = wl4[(k * 8 + g) * 64 + lane];
#pragma unroll
                for (int e = 0; e < 4; ++e) {
                    acc[e][k] += xq[e].x * wv.x;
                    acc[e][k] += xq[e].y * wv.y;
                    acc[e][k] += xq[e].z * wv.z;
                    acc[e][k] += xq[e].w * wv.w;
                }
            }
        }
#pragma unroll
        for (int e = 0; e < 4; ++e) {
            if (srcs[e] < 0) continue;   // bucket padding
            float msg = w4s[e].x * acc[e][0] + w4s[e].y * acc[e][1] +
                        w4s[e].z * acc[e][2] + w4s[e].w * acc[e][3];
            atomicAdd(&agg2[dsts[e] * 64 + lane], msg);
        }
    }
}

// ---------- conv2 finish + pool2 (fused: same geometry) ----------

__global__ void conv2fin_pool2(const float* __restrict__ x1, const float* __restrict__ root2,
                               const float* __restrict__ bias2, const float* __restrict__ cnt2,
                               const float* __restrict__ agg2, const int* __restrict__ cl2,
                               const int* __restrict__ batch1, unsigned* __restrict__ x2key,
                               int* __restrict__ ccnt2, int* __restrict__ batch2) {
    int gid = blockIdx.x * blockDim.x + threadIdx.x;
    if (gid >= NP1 * 64) return;
    int n = gid >> 6, f = gid & 63;
    float r = 0.0f;
    const float* xs = x1 + n * 32;
#pragma unroll
    for (int i = 0; i < 32; ++i) r += xs[i] * root2[i * 64 + f];
    float v = elu1(agg2[gid] / fmaxf(cnt2[n], 1.0f) + r + bias2[f]);
    int c = cl2[n];
    atomicMax(&x2key[c * 64 + f], fkey(v));
    if (f == 0) {
        atomicAdd(&ccnt2[c], 1);
        atomicMax(&batch2[c], batch1[n]);
    }
}

// ---------- global mean pool: per-block LDS partials, no global atomics ----------

__global__ __launch_bounds__(256) void pool2_part(const unsigned* __restrict__ x2key,
                                                  const int* __restrict__ ccnt2,
                                                  const int* __restrict__ batch2,
                                                  float* __restrict__ partial,
                                                  float* __restrict__ pcnt) {
    __shared__ float gs[GG * 64 + GG];
    const int t = threadIdx.x;
    for (int i = t; i < GG * 64 + GG; i += 256) gs[i] = 0.0f;
    __syncthreads();
    const int lane = t & 63, wv = t >> 6;
    const int c0 = blockIdx.x * CPB2;
    const int c1 = min(c0 + CPB2, NP2);
    for (int c = c0 + wv; c < c1; c += 4) {
        int cnt = ccnt2[c];
        int g = batch2[c];
        float v = cnt > 0 ? fkey_inv(x2key[c * 64 + lane]) : 0.0f;
        atomicAdd(&gs[g * 64 + lane], v);
        if (lane == 0) atomicAdd(&gs[GG * 64 + g], 1.0f);
    }
    __syncthreads();
    float* pb = partial + (size_t)blockIdx.x * (GG * 64);
    for (int i = t; i < GG * 64; i += 256) pb[i] = gs[i];
    if (t < GG) pcnt[blockIdx.x * GG + t] = gs[GG * 64 + t];
}

// ---------- fused partial-reduce + head (one block per graph) ----------

__global__ __launch_bounds__(128) void gpool_head(const float* __restrict__ partial,
                                                  const float* __restrict__ pcnt,
                                                  const float* __restrict__ fc1w,
                                                  const float* __restrict__ fc1b,
                                                  const float* __restrict__ fc2w,
                                                  const float* __restrict__ fc2b,
                                                  float* __restrict__ out) {
    const int g = blockIdx.x;
    const int t = threadIdx.x;  // 128
    __shared__ float red[128];
    __shared__ float acc2[128];
    __shared__ float gm[64];
    __shared__ float h3[128];
    __shared__ float lg[3];

    red[t] = (t < PB2) ? pcnt[t * GG + g] : 0.0f;
    __syncthreads();
    for (int s = 64; s > 0; s >>= 1) {
        if (t < s) red[t] += red[t + s];
        __syncthreads();
    }

    const int f = t & 63, h = t >> 6;
    float acc = 0.0f;
    for (int b = h * (PB2 / 2); b < (h + 1) * (PB2 / 2); ++b)
        acc += partial[(size_t)b * (GG * 64) + g * 64 + f];
    acc2[t] = acc;
    __syncthreads();
    if (t < 64) gm[t] = (acc2[t] + acc2[t + 64]) / fmaxf(red[0], 1.0f);
    __syncthreads();

    float a = fc1b[t];
#pragma unroll
    for (int i = 0; i < 64; ++i) a += gm[i] * fc1w[i * 128 + t];
    h3[t] = elu1(a);
    __syncthreads();
    if (t < 3) {
        float a2 = fc2b[t];
#pragma unroll
        for (int i = 0; i < 128; ++i) a2 += h3[i] * fc2w[i * 3 + t];
        lg[t] = a2;
    }
    __syncthreads();
    if (t == 0) {
        float m = fmaxf(lg[0], fmaxf(lg[1], lg[2]));
        float s = expf(lg[0] - m) + expf(lg[1] - m) + expf(lg[2] - m);
        float lse = m + logf(s);
        out[g * 3 + 0] = lg[0] - lse;
        out[g * 3 + 1] = lg[1] - lse;
        out[g * 3 + 2] = lg[2] - lse;
    }
}

// ---------- launcher ----------

extern "C" void kernel_launch(void* const* d_in, const int* in_sizes, int n_in,
                              void* d_out, int out_size, void* d_ws, size_t ws_size,
                              hipStream_t stream) {
    const float* x     = (const float*)d_in[0];
    const float* pos   = (const float*)d_in[1];
    const float* eattr = (const float*)d_in[2];
    const int*   ei    = (const int*)d_in[3];
    const int*   batch = (const int*)d_in[4];
    const int*   cl1   = (const int*)d_in[5];
    const int*   ei2   = (const int*)d_in[6];
    const int*   cl2   = (const int*)d_in[7];
    const float* W1    = (const float*)d_in[8];
    const float* root1 = (const float*)d_in[9];
    const float* bias1 = (const float*)d_in[10];
    const float* W2    = (const float*)d_in[11];
    const float* root2 = (const float*)d_in[12];
    const float* bias2 = (const float*)d_in[13];
    const float* fc1w  = (const float*)d_in[14];
    const float* fc1b  = (const float*)d_in[15];
    const float* fc2w  = (const float*)d_in[16];
    const float* fc2b  = (const float*)d_in[17];
    float* out = (float*)d_out;

    char* p = (char*)d_ws;
    auto carve = [&](size_t bytes) {
        char* r = p;
        p += (bytes + 255) & ~(size_t)255;
        return r;
    };
    // regions needing zero-init first, fully-overwritten regions last
    float*    agg1    = (float*)carve((size_t)NN * 32 * 4);
    float*    cnt1    = (float*)carve((size_t)NN * 4);
    unsigned* x1key   = (unsigned*)carve((size_t)NP1 * 32 * 4);  // becomes float x1 in-place
    int*      ccnt1   = (int*)carve((size_t)NP1 * 4);
    float*    pos1    = (float*)carve((size_t)NP1 * 2 * 4);
    int*      batch1  = (int*)carve((size_t)NP1 * 4);
    unsigned* scaleb  = (unsigned*)carve(4);
    float*    agg2    = (float*)carve((size_t)NP1 * 64 * 4);
    float*    cnt2    = (float*)carve((size_t)NP1 * 4);
    unsigned* x2key   = (unsigned*)carve((size_t)NP2 * 64 * 4);
    int*      ccnt2   = (int*)carve((size_t)NP2 * 4);
    int*      batch2  = (int*)carve((size_t)NP2 * 4);
    int*      ccount  = (int*)carve(25 * 4);
    size_t zero_bytes = (size_t)(p - (char*)d_ws);
    int*      aoff    = (int*)carve(26 * 4);
    int*      gcursor = (int*)carve(25 * 4);
    float*    cart    = (float*)carve((size_t)EE2 * 2 * 4);
    float*    partial = (float*)carve((size_t)PB2 * GG * 64 * 4);
    float*    pcnt    = (float*)carve((size_t)PB2 * GG * 4);

    // bucket arrays alias agg1 (dead after conv1fin_pool1): 4.47MB <= 7.68MB
    int*    bsrc = (int*)agg1;
    int*    bdst = bsrc + PAD256;
    float4* bw   = (float4*)(bdst + PAD256);

    hipMemsetAsync(d_ws, 0, zero_bytes, stream);

    const int B = 256;
    conv1_edge<<<(EE * 32 + B - 1) / B, B, 0, stream>>>(x, eattr, ei, W1, agg1, cnt1);
    conv1fin_pool1<<<(NN * 32 + B - 1) / B, B, 0, stream>>>(x, root1, bias1, cnt1, agg1,
                                                            pos, batch, cl1, x1key, ccnt1,
                                                            pos1, batch1);
    pool1_fin<<<(NP1 * 32 + B - 1) / B, B, 0, stream>>>(x1key, ccnt1, pos1);
    // agg1 dead from here; mark bucket padding entries invalid
    hipMemsetAsync(bsrc, 0xFF, (size_t)PAD256 * 4, stream);
    cart_k<<<(EE2 + B - 1) / B, B, 0, stream>>>(pos1, ei2, cart, scaleb, cnt2);
    bucket_count<<<(EE2 + B - 1) / B, B, 0, stream>>>(cart, scaleb, ccount);
    bucket_scan<<<1, 64, 0, stream>>>(ccount, aoff, gcursor);
    bucket_scatter<<<(EE2 + B - 1) / B, B, 0, stream>>>(cart, scaleb, ei2, gcursor, bsrc, bdst, bw);
    conv2_cell<<<NB2, 256, 0, stream>>>(bsrc, bdst, bw, aoff, (const float*)x1key, W2, agg2);
    conv2fin_pool2<<<(NP1 * 64 + B - 1) / B, B, 0, stream>>>((const float*)x1key, root2, bias2,
                                                             cnt2, agg2, cl2, batch1, x2key,
                                                             ccnt2, batch2);
    pool2_part<<<PB2, 256, 0, stream>>>(x2key, ccnt2, batch2, partial, pcnt);
    gpool_head<<<GG, 128, 0, stream>>>(partial, pcnt, fc1w, fc1b, fc2w, fc2b, out);
}

// Round 10
// 360.378 us; speedup vs baseline: 1.0029x; 1.0029x over previous
//
#include <hip/hip_runtime.h>
#include <math.h>

#define KD 5
#define NN 60000
#define EE 360000
#define NP1 30000
#define EE2 180000
#define NP2 15000
#define GG 60

// conv2 bucketing (256-aligned buckets, one cell per 256-thread block)
#define PAD256 (EE2 + 25 * 256)         // 186400 worst-case padded total
#define NB2 ((PAD256 + 255) / 256)      // 729 blocks

// pool2/global-pool partials
#define PB2 120
#define CPB2 125   // ceil(NP2 / PB2)

// ---------- helpers ----------

__device__ __forceinline__ unsigned fkey(float f) {
    unsigned u = __float_as_uint(f);
    return (u & 0x80000000u) ? ~u : (u | 0x80000000u);
}
__device__ __forceinline__ float fkey_inv(unsigned k) {
    unsigned u = (k & 0x80000000u) ? (k ^ 0x80000000u) : ~k;
    return __uint_as_float(u);
}

__device__ __forceinline__ void spline_basis(float p0, float p1, int* idx, float* w) {
    float v0 = p0 * 4.0f, v1 = p1 * 4.0f;
    float fl0 = floorf(v0), fl1 = floorf(v1);
    int i0 = min(max((int)fl0, 0), KD - 1);
    int i1 = min(max((int)fl1, 0), KD - 1);
    float fr0 = v0 - fl0, fr1 = v1 - fl1;
    int c = 0;
#pragma unroll
    for (int s0 = 0; s0 < 2; ++s0) {
#pragma unroll
        for (int s1 = 0; s1 < 2; ++s1) {
            int ix = min(i0 + s0, KD - 1);
            int iy = min(i1 + s1, KD - 1);
            float w0 = s0 ? fr0 : 1.0f - fr0;
            float w1 = s1 ? fr1 : 1.0f - fr1;
            idx[c] = ix + KD * iy;
            w[c] = w0 * w1;
            ++c;
        }
    }
}

// cell + basis weights from RAW cartesian attr (applies the scale transform
// inline, bit-identical to attr2 = c/(2s)+0.5 then v = attr*4)
__device__ __forceinline__ void cell_basis(float c0, float c1, float s,
                                           int& cell, float4& w4) {
    float p0 = c0 / (2.0f * s) + 0.5f;
    float p1 = c1 / (2.0f * s) + 0.5f;
    float v0 = p0 * 4.0f, v1 = p1 * 4.0f;
    float fl0 = floorf(v0), fl1 = floorf(v1);
    int i0 = min(max((int)fl0, 0), KD - 1);
    int i1 = min(max((int)fl1, 0), KD - 1);
    float fr0 = v0 - fl0, fr1 = v1 - fl1;
    cell = i0 + 5 * i1;
    w4.x = (1.0f - fr0) * (1.0f - fr1);  // k=0 (s0=0,s1=0)
    w4.y = (1.0f - fr0) * fr1;           // k=1 (s0=0,s1=1)
    w4.z = fr0 * (1.0f - fr1);           // k=2 (s0=1,s1=0)
    w4.w = fr0 * fr1;                    // k=3 (s0=1,s1=1)
}

__device__ __forceinline__ float elu1(float v) {
    return v > 0.0f ? v : expm1f(v);
}

// ---------- conv1 ----------

__global__ void conv1_edge(const float* __restrict__ x, const float* __restrict__ ea,
                           const int* __restrict__ ei, const float* __restrict__ W1,
                           float* __restrict__ agg1, float* __restrict__ cnt1) {
    int gid = blockIdx.x * blockDim.x + threadIdx.x;
    if (gid >= EE * 32) return;
    int e = gid >> 5, f = gid & 31;
    int src = ei[e], dst = ei[EE + e];
    int idx[4]; float w[4];
    spline_basis(ea[2 * e], ea[2 * e + 1], idx, w);
    float coeff = 0.0f;
#pragma unroll
    for (int k = 0; k < 4; ++k) coeff += w[k] * W1[idx[k] * 32 + f];
    atomicAdd(&agg1[dst * 32 + f], x[src] * coeff);
    if (f == 0) atomicAdd(&cnt1[dst], 1.0f);
}

// ---------- conv1 finish + pool1 (fused: same geometry, h kept in-register) ----------

__global__ void conv1fin_pool1(const float* __restrict__ x, const float* __restrict__ root1,
                               const float* __restrict__ bias1, const float* __restrict__ cnt1,
                               const float* __restrict__ agg1, const float* __restrict__ pos,
                               const int* __restrict__ batch, const int* __restrict__ cl1,
                               unsigned* __restrict__ x1key, int* __restrict__ ccnt1,
                               float* __restrict__ pos1, int* __restrict__ batch1) {
    int gid = blockIdx.x * blockDim.x + threadIdx.x;
    if (gid >= NN * 32) return;
    int n = gid >> 5, f = gid & 31;
    float v = elu1(agg1[gid] / fmaxf(cnt1[n], 1.0f) + x[n] * root1[f] + bias1[f]);
    int c = cl1[n];
    atomicMax(&x1key[c * 32 + f], fkey(v));
    if (f == 0) {
        atomicAdd(&ccnt1[c], 1);
        atomicAdd(&pos1[c * 2], pos[n * 2]);
        atomicAdd(&pos1[c * 2 + 1], pos[n * 2 + 1]);
        atomicMax(&batch1[c], batch[n]);
    }
}

__global__ void pool1_fin(unsigned* __restrict__ x1key, const int* __restrict__ ccnt1,
                          float* __restrict__ pos1) {
    int gid = blockIdx.x * blockDim.x + threadIdx.x;
    if (gid >= NP1 * 32) return;
    int c = gid >> 5, f = gid & 31;
    int cnt = ccnt1[c];
    float v = cnt > 0 ? fkey_inv(x1key[gid]) : 0.0f;
    ((float*)x1key)[gid] = v;
    if (f < 2) pos1[c * 2 + f] = pos1[c * 2 + f] / fmaxf((float)cnt, 1.0f);
}

// ---------- cartesian (stores RAW cart; also counts cnt2 per dst) ----------

__global__ void cart_k(const float* __restrict__ pos1, const int* __restrict__ ei2,
                       float* __restrict__ cart, unsigned* __restrict__ scaleb,
                       float* __restrict__ cnt2) {
    int e = blockIdx.x * blockDim.x + threadIdx.x;
    float m = 0.0f;
    if (e < EE2) {
        int s = ei2[e], d = ei2[EE2 + e];
        float c0 = pos1[d * 2] - pos1[s * 2];
        float c1 = pos1[d * 2 + 1] - pos1[s * 2 + 1];
        cart[e * 2] = c0;
        cart[e * 2 + 1] = c1;
        m = fmaxf(fabsf(c0), fabsf(c1));
        atomicAdd(&cnt2[d], 1.0f);
    }
#pragma unroll
    for (int off = 32; off > 0; off >>= 1) m = fmaxf(m, __shfl_down(m, off));
    if ((threadIdx.x & 63) == 0) atomicMax(scaleb, __float_as_uint(m));
}

// ---------- conv2 bucketing by B-spline cell ----------

__global__ void bucket_count(const float* __restrict__ cart,
                             const unsigned* __restrict__ scaleb,
                             int* __restrict__ ccount) {
    __shared__ int lc[25];
    int t = threadIdx.x;
    if (t < 25) lc[t] = 0;
    __syncthreads();
    int e = blockIdx.x * blockDim.x + t;
    if (e < EE2) {
        float s = fmaxf(__uint_as_float(*scaleb), 1e-12f);
        int cell; float4 w4;
        cell_basis(cart[2 * e], cart[2 * e + 1], s, cell, w4);
        atomicAdd(&lc[cell], 1);
    }
    __syncthreads();
    if (t < 25 && lc[t] > 0) atomicAdd(&ccount[t], lc[t]);
}

__global__ void bucket_scan(const int* __restrict__ ccount, int* __restrict__ aoff,
                            int* __restrict__ gcursor) {
    if (blockIdx.x == 0 && threadIdx.x == 0) {
        int acc = 0;
        for (int c = 0; c < 25; ++c) {
            aoff[c] = acc;
            gcursor[c] = acc;
            acc += (ccount[c] + 255) & ~255;   // 256-align each bucket
        }
        aoff[25] = acc;
    }
}

__global__ void bucket_scatter(const float* __restrict__ cart,
                               const unsigned* __restrict__ scaleb,
                               const int* __restrict__ ei2,
                               int* __restrict__ gcursor,
                               int* __restrict__ bsrc, int* __restrict__ bdst,
                               float4* __restrict__ bw) {
    __shared__ int lc[25], lb[25];
    int t = threadIdx.x;
    if (t < 25) lc[t] = 0;
    __syncthreads();
    int e = blockIdx.x * blockDim.x + t;
    bool valid = e < EE2;
    int cell = 0, rank = 0;
    float4 w4 = make_float4(0.f, 0.f, 0.f, 0.f);
    if (valid) {
        float s = fmaxf(__uint_as_float(*scaleb), 1e-12f);
        cell_basis(cart[2 * e], cart[2 * e + 1], s, cell, w4);
        rank = atomicAdd(&lc[cell], 1);
    }
    __syncthreads();
    if (t < 25) lb[t] = lc[t] > 0 ? atomicAdd(&gcursor[t], lc[t]) : 0;
    __syncthreads();
    if (valid) {
        int pos = lb[cell] + rank;
        bsrc[pos] = ei2[e];
        bdst[pos] = ei2[EE2 + e];
        bw[pos] = w4;
    }
}

// ---------- conv2: one cell per block, weights in LDS, 4 edges in flight ----------
// Weight LDS layout (fi-quad transposed): float4 unit u = (k*8+g)*64 + fout
// holds W2[slot_k][g*4 .. g*4+3][fout]. Each ds_read_b128 is reused by the
// 4 in-flight edges -> LDS weight traffic / 4 = 1.47GB (~19us floor), FMA
// 1.47G MAC (~19us floor). No register-residency fight (acc/xq ~80 VGPR).

__global__ __launch_bounds__(256) void conv2_cell(const int* __restrict__ bsrc,
                                                  const int* __restrict__ bdst,
                                                  const float4* __restrict__ bw,
                                                  const int* __restrict__ aoff,
                                                  const float* __restrict__ x1,
                                                  const float* __restrict__ W2,
                                                  float* __restrict__ agg2) {
    __shared__ float wl[4 * 8 * 64 * 4];   // 32KB
    __shared__ int soff[26];
    const int t = threadIdx.x;
    if (t < 26) soff[t] = aoff[t];
    __syncthreads();
    const int base = blockIdx.x * 256;
    if (base >= soff[25]) return;          // uniform over block
    int cell = 0;
#pragma unroll
    for (int c = 1; c < 25; ++c) cell += (base >= soff[c]) ? 1 : 0;
    const int cx = cell % 5, cy = cell / 5;

    // stage this cell's 4-slot weight block (coalesced global read)
    for (int i = t; i < 8192; i += 256) {
        int s  = i >> 11;          // k slot index 0..3
        int fi = (i >> 6) & 31;
        int fo = i & 63;
        int slot = min(cx + (s >> 1), 4) + 5 * min(cy + (s & 1), 4);
        wl[(((s * 8 + (fi >> 2)) * 64) + fo) * 4 + (fi & 3)] = W2[slot * 2048 + fi * 64 + fo];
    }
    __syncthreads();

    const int lane = t & 63;
    const int wbase = base + (t >> 6) * 64;   // this wave's 64-edge segment
    const float4* wl4 = (const float4*)wl;

    for (int q = 0; q < 64; q += 4) {
        const int e0 = wbase + q;
        int srcs[4], dsts[4];
        float4 w4s[4];
#pragma unroll
        for (int e = 0; e < 4; ++e) {
            srcs[e] = bsrc[e0 + e];
            dsts[e] = bdst[e0 + e];
            w4s[e] = bw[e0 + e];
        }
        float acc[4][4] = {};   // [edge][k]
#pragma unroll
        for (int g = 0; g < 8; ++g) {
            float4 xq[4];
#pragma unroll
            for (int e = 0; e < 4; ++e)
                xq[e] = (srcs[e] >= 0) ? *(const float4*)(x1 + srcs[e] * 32 + g * 4)
                                       : make_float4(0.f, 0.f, 0.f, 0.f);
#pragma unroll
            for (int k = 0; k < 4; ++k) {
                float4 wv = wl4[(k * 8 + g) * 64 + lane];
#pragma unroll
                for (int e = 0; e < 4; ++e) {
                    acc[e][k] += xq[e].x * wv.x;
                    acc[e][k] += xq[e].y * wv.y;
                    acc[e][k] += xq[e].z * wv.z;
                    acc[e][k] += xq[e].w * wv.w;
                }
            }
        }
#pragma unroll
        for (int e = 0; e < 4; ++e) {
            if (srcs[e] < 0) continue;   // bucket padding
            float msg = w4s[e].x * acc[e][0] + w4s[e].y * acc[e][1] +
                        w4s[e].z * acc[e][2] + w4s[e].w * acc[e][3];
            atomicAdd(&agg2[dsts[e] * 64 + lane], msg);
        }
    }
}

// ---------- conv2 finish + pool2 (fused: same geometry) ----------

__global__ void conv2fin_pool2(const float* __restrict__ x1, const float* __restrict__ root2,
                               const float* __restrict__ bias2, const float* __restrict__ cnt2,
                               const float* __restrict__ agg2, const int* __restrict__ cl2,
                               const int* __restrict__ batch1, unsigned* __restrict__ x2key,
                               int* __restrict__ ccnt2, int* __restrict__ batch2) {
    int gid = blockIdx.x * blockDim.x + threadIdx.x;
    if (gid >= NP1 * 64) return;
    int n = gid >> 6, f = gid & 63;
    float r = 0.0f;
    const float* xs = x1 + n * 32;
#pragma unroll
    for (int i = 0; i < 32; ++i) r += xs[i] * root2[i * 64 + f];
    float v = elu1(agg2[gid] / fmaxf(cnt2[n], 1.0f) + r + bias2[f]);
    int c = cl2[n];
    atomicMax(&x2key[c * 64 + f], fkey(v));
    if (f == 0) {
        atomicAdd(&ccnt2[c], 1);
        atomicMax(&batch2[c], batch1[n]);
    }
}

// ---------- global mean pool: per-block LDS partials, no global atomics ----------

__global__ __launch_bounds__(256) void pool2_part(const unsigned* __restrict__ x2key,
                                                  const int* __restrict__ ccnt2,
                                                  const int* __restrict__ batch2,
                                                  float* __restrict__ partial,
                                                  float* __restrict__ pcnt) {
    __shared__ float gs[GG * 64 + GG];
    const int t = threadIdx.x;
    for (int i = t; i < GG * 64 + GG; i += 256) gs[i] = 0.0f;
    __syncthreads();
    const int lane = t & 63, wv = t >> 6;
    const int c0 = blockIdx.x * CPB2;
    const int c1 = min(c0 + CPB2, NP2);
    for (int c = c0 + wv; c < c1; c += 4) {
        int cnt = ccnt2[c];
        int g = batch2[c];
        float v = cnt > 0 ? fkey_inv(x2key[c * 64 + lane]) : 0.0f;
        atomicAdd(&gs[g * 64 + lane], v);
        if (lane == 0) atomicAdd(&gs[GG * 64 + g], 1.0f);
    }
    __syncthreads();
    float* pb = partial + (size_t)blockIdx.x * (GG * 64);
    for (int i = t; i < GG * 64; i += 256) pb[i] = gs[i];
    if (t < GG) pcnt[blockIdx.x * GG + t] = gs[GG * 64 + t];
}

// ---------- fused partial-reduce + head (one block per graph) ----------

__global__ __launch_bounds__(128) void gpool_head(const float* __restrict__ partial,
                                                  const float* __restrict__ pcnt,
                                                  const float* __restrict__ fc1w,
                                                  const float* __restrict__ fc1b,
                                                  const float* __restrict__ fc2w,
                                                  const float* __restrict__ fc2b,
                                                  float* __restrict__ out) {
    const int g = blockIdx.x;
    const int t = threadIdx.x;  // 128
    __shared__ float red[128];
    __shared__ float acc2[128];
    __shared__ float gm[64];
    __shared__ float h3[128];
    __shared__ float lg[3];

    red[t] = (t < PB2) ? pcnt[t * GG + g] : 0.0f;
    __syncthreads();
    for (int s = 64; s > 0; s >>= 1) {
        if (t < s) red[t] += red[t + s];
        __syncthreads();
    }

    const int f = t & 63, h = t >> 6;
    float acc = 0.0f;
    for (int b = h * (PB2 / 2); b < (h + 1) * (PB2 / 2); ++b)
        acc += partial[(size_t)b * (GG * 64) + g * 64 + f];
    acc2[t] = acc;
    __syncthreads();
    if (t < 64) gm[t] = (acc2[t] + acc2[t + 64]) / fmaxf(red[0], 1.0f);
    __syncthreads();

    float a = fc1b[t];
#pragma unroll
    for (int i = 0; i < 64; ++i) a += gm[i] * fc1w[i * 128 + t];
    h3[t] = elu1(a);
    __syncthreads();
    if (t < 3) {
        float a2 = fc2b[t];
#pragma unroll
        for (int i = 0; i < 128; ++i) a2 += h3[i] * fc2w[i * 3 + t];
        lg[t] = a2;
    }
    __syncthreads();
    if (t == 0) {
        float m = fmaxf(lg[0], fmaxf(lg[1], lg[2]));
        float s = expf(lg[0] - m) + expf(lg[1] - m) + expf(lg[2] - m);
        float lse = m + logf(s);
        out[g * 3 + 0] = lg[0] - lse;
        out[g * 3 + 1] = lg[1] - lse;
        out[g * 3 + 2] = lg[2] - lse;
    }
}

// ---------- launcher ----------

extern "C" void kernel_launch(void* const* d_in, const int* in_sizes, int n_in,
                              void* d_out, int out_size, void* d_ws, size_t ws_size,
                              hipStream_t stream) {
    const float* x     = (const float*)d_in[0];
    const float* pos   = (const float*)d_in[1];
    const float* eattr = (const float*)d_in[2];
    const int*   ei    = (const int*)d_in[3];
    const int*   batch = (const int*)d_in[4];
    const int*   cl1   = (const int*)d_in[5];
    const int*   ei2   = (const int*)d_in[6];
    const int*   cl2   = (const int*)d_in[7];
    const float* W1    = (const float*)d_in[8];
    const float* root1 = (const float*)d_in[9];
    const float* bias1 = (const float*)d_in[10];
    const float* W2    = (const float*)d_in[11];
    const float* root2 = (const float*)d_in[12];
    const float* bias2 = (const float*)d_in[13];
    const float* fc1w  = (const float*)d_in[14];
    const float* fc1b  = (const float*)d_in[15];
    const float* fc2w  = (const float*)d_in[16];
    const float* fc2b  = (const float*)d_in[17];
    float* out = (float*)d_out;

    char* p = (char*)d_ws;
    auto carve = [&](size_t bytes) {
        char* r = p;
        p += (bytes + 255) & ~(size_t)255;
        return r;
    };
    // regions needing zero-init first, fully-overwritten regions last
    float*    agg1    = (float*)carve((size_t)NN * 32 * 4);
    float*    cnt1    = (float*)carve((size_t)NN * 4);
    unsigned* x1key   = (unsigned*)carve((size_t)NP1 * 32 * 4);  // becomes float x1 in-place
    int*      ccnt1   = (int*)carve((size_t)NP1 * 4);
    float*    pos1    = (float*)carve((size_t)NP1 * 2 * 4);
    int*      batch1  = (int*)carve((size_t)NP1 * 4);
    unsigned* scaleb  = (unsigned*)carve(4);
    float*    agg2    = (float*)carve((size_t)NP1 * 64 * 4);
    float*    cnt2    = (float*)carve((size_t)NP1 * 4);
    unsigned* x2key   = (unsigned*)carve((size_t)NP2 * 64 * 4);
    int*      ccnt2   = (int*)carve((size_t)NP2 * 4);
    int*      batch2  = (int*)carve((size_t)NP2 * 4);
    int*      ccount  = (int*)carve(25 * 4);
    size_t zero_bytes = (size_t)(p - (char*)d_ws);
    int*      aoff    = (int*)carve(26 * 4);
    int*      gcursor = (int*)carve(25 * 4);
    float*    cart    = (float*)carve((size_t)EE2 * 2 * 4);
    float*    partial = (float*)carve((size_t)PB2 * GG * 64 * 4);
    float*    pcnt    = (float*)carve((size_t)PB2 * GG * 4);

    // bucket arrays alias agg1 (dead after conv1fin_pool1): 4.47MB <= 7.68MB
    int*    bsrc = (int*)agg1;
    int*    bdst = bsrc + PAD256;
    float4* bw   = (float4*)(bdst + PAD256);

    hipMemsetAsync(d_ws, 0, zero_bytes, stream);

    const int B = 256;
    conv1_edge<<<(EE * 32 + B - 1) / B, B, 0, stream>>>(x, eattr, ei, W1, agg1, cnt1);
    conv1fin_pool1<<<(NN * 32 + B - 1) / B, B, 0, stream>>>(x, root1, bias1, cnt1, agg1,
                                                            pos, batch, cl1, x1key, ccnt1,
                                                            pos1, batch1);
    pool1_fin<<<(NP1 * 32 + B - 1) / B, B, 0, stream>>>(x1key, ccnt1, pos1);
    // agg1 dead from here; mark bucket padding entries invalid
    hipMemsetAsync(bsrc, 0xFF, (size_t)PAD256 * 4, stream);
    cart_k<<<(EE2 + B - 1) / B, B, 0, stream>>>(pos1, ei2, cart, scaleb, cnt2);
    bucket_count<<<(EE2 + B - 1) / B, B, 0, stream>>>(cart, scaleb, ccount);
    bucket_scan<<<1, 64, 0, stream>>>(ccount, aoff, gcursor);
    bucket_scatter<<<(EE2 + B - 1) / B, B, 0, stream>>>(cart, scaleb, ei2, gcursor, bsrc, bdst, bw);
    conv2_cell<<<NB2, 256, 0, stream>>>(bsrc, bdst, bw, aoff, (const float*)x1key, W2, agg2);
    conv2fin_pool2<<<(NP1 * 64 + B - 1) / B, B, 0, stream>>>((const float*)x1key, root2, bias2,
                                                             cnt2, agg2, cl2, batch1, x2key,
                                                             ccnt2, batch2);
    pool2_part<<<PB2, 256, 0, stream>>>(x2key, ccnt2, batch2, partial, pcnt);
    gpool_head<<<GG, 128, 0, stream>>>(partial, pcnt, fc1w, fc1b, fc2w, fc2b, out);
}

// Round 11
// 301.529 us; speedup vs baseline: 1.1986x; 1.1952x over previous
//
#include <hip/hip_runtime.h>
#include <math.h>

#define KD 5
#define NN 60000
#define EE 360000
#define NP1 30000
#define EE2 180000
#define NP2 15000
#define GG 60

// conv2 tiling (R2-proven)
#define FH 16      // fout quarter width
#define NBLK 512   // edge blocks per quarter

// pool2/global-pool partials
#define PB2 120
#define CPB2 125   // ceil(NP2 / PB2)

// ---------- helpers ----------

__device__ __forceinline__ unsigned fkey(float f) {
    unsigned u = __float_as_uint(f);
    return (u & 0x80000000u) ? ~u : (u | 0x80000000u);
}
__device__ __forceinline__ float fkey_inv(unsigned k) {
    unsigned u = (k & 0x80000000u) ? (k ^ 0x80000000u) : ~k;
    return __uint_as_float(u);
}

__device__ __forceinline__ void spline_basis(float p0, float p1, int* idx, float* w) {
    float v0 = p0 * 4.0f, v1 = p1 * 4.0f;
    float fl0 = floorf(v0), fl1 = floorf(v1);
    int i0 = min(max((int)fl0, 0), KD - 1);
    int i1 = min(max((int)fl1, 0), KD - 1);
    float fr0 = v0 - fl0, fr1 = v1 - fl1;
    int c = 0;
#pragma unroll
    for (int s0 = 0; s0 < 2; ++s0) {
#pragma unroll
        for (int s1 = 0; s1 < 2; ++s1) {
            int ix = min(i0 + s0, KD - 1);
            int iy = min(i1 + s1, KD - 1);
            float w0 = s0 ? fr0 : 1.0f - fr0;
            float w1 = s1 ? fr1 : 1.0f - fr1;
            idx[c] = ix + KD * iy;
            w[c] = w0 * w1;
            ++c;
        }
    }
}

__device__ __forceinline__ float elu1(float v) {
    return v > 0.0f ? v : expm1f(v);
}

// ---------- conv1: 25-slot basis aggregation (4 atomics/edge vs 32; Fin=1) ----------
// agg[dst,f] = sum_e x[src]*sum_k w_k*W1[slot_k,f] = sum_s agg25[dst,s]*W1[s,f]

__global__ void conv1_edge25(const float* __restrict__ x, const float* __restrict__ ea,
                             const int* __restrict__ ei, float* __restrict__ agg25,
                             float* __restrict__ cnt1) {
    int e = blockIdx.x * blockDim.x + threadIdx.x;
    if (e >= EE) return;
    int src = ei[e], dst = ei[EE + e];
    int idx[4]; float w[4];
    spline_basis(ea[2 * e], ea[2 * e + 1], idx, w);
    float xs = x[src];
#pragma unroll
    for (int k = 0; k < 4; ++k) atomicAdd(&agg25[dst * 25 + idx[k]], w[k] * xs);
    atomicAdd(&cnt1[dst], 1.0f);
}

// conv1 finish (25->32 GEMM via LDS-staged coefficients) + elu + pool1, fused.
// Block = 256 threads = 8 nodes x 32 f. NN = 60000 = 7500*8 exactly.

__global__ __launch_bounds__(256) void conv1gemm_pool1(
        const float* __restrict__ x, const float* __restrict__ W1,
        const float* __restrict__ root1, const float* __restrict__ bias1,
        const float* __restrict__ cnt1, const float* __restrict__ agg25,
        const float* __restrict__ pos, const int* __restrict__ batch,
        const int* __restrict__ cl1, unsigned* __restrict__ x1key,
        int* __restrict__ ccnt1, float* __restrict__ pos1,
        int* __restrict__ batch1) {
    __shared__ float a25[8][25];
    const int nb = blockIdx.x * 8;
    const int t = threadIdx.x;
    for (int i = t; i < 8 * 25; i += 256)
        a25[i / 25][i % 25] = agg25[nb * 25 + i];   // contiguous 200-float stage
    __syncthreads();
    const int nn = t >> 5, f = t & 31;
    const int n = nb + nn;
    float dot = 0.0f;
#pragma unroll
    for (int s = 0; s < 25; ++s) dot += a25[nn][s] * W1[s * 32 + f];  // LDS broadcast
    float v = elu1(dot / fmaxf(cnt1[n], 1.0f) + x[n] * root1[f] + bias1[f]);
    int c = cl1[n];
    atomicMax(&x1key[c * 32 + f], fkey(v));
    if (f == 0) {
        atomicAdd(&ccnt1[c], 1);
        atomicAdd(&pos1[c * 2], pos[n * 2]);
        atomicAdd(&pos1[c * 2 + 1], pos[n * 2 + 1]);
        atomicMax(&batch1[c], batch[n]);
    }
}

__global__ void pool1_fin(unsigned* __restrict__ x1key, const int* __restrict__ ccnt1,
                          float* __restrict__ pos1) {
    int gid = blockIdx.x * blockDim.x + threadIdx.x;
    if (gid >= NP1 * 32) return;
    int c = gid >> 5, f = gid & 31;
    int cnt = ccnt1[c];
    float v = cnt > 0 ? fkey_inv(x1key[gid]) : 0.0f;
    ((float*)x1key)[gid] = v;
    if (f < 2) pos1[c * 2 + f] = pos1[c * 2 + f] / fmaxf((float)cnt, 1.0f);
}

// ---------- cartesian ----------

__global__ void cart_k(const float* __restrict__ pos1, const int* __restrict__ ei2,
                       float* __restrict__ attr2, unsigned* __restrict__ scaleb) {
    int e = blockIdx.x * blockDim.x + threadIdx.x;
    float m = 0.0f;
    if (e < EE2) {
        int s = ei2[e], d = ei2[EE2 + e];
        float c0 = pos1[d * 2] - pos1[s * 2];
        float c1 = pos1[d * 2 + 1] - pos1[s * 2 + 1];
        attr2[e * 2] = c0;
        attr2[e * 2 + 1] = c1;
        m = fmaxf(fabsf(c0), fabsf(c1));
    }
#pragma unroll
    for (int off = 32; off > 0; off >>= 1) m = fmaxf(m, __shfl_down(m, off));
    if ((threadIdx.x & 63) == 0) atomicMax(scaleb, __float_as_uint(m));
}

__global__ void attr2_fin(float* __restrict__ attr2, const unsigned* __restrict__ scaleb) {
    int gid = blockIdx.x * blockDim.x + threadIdx.x;
    if (gid >= EE2 * 2) return;
    float s = fmaxf(__uint_as_float(*scaleb), 1e-12f);
    attr2[gid] = attr2[gid] / (2.0f * s) + 0.5f;
}

// ---------- conv2: W2 staged in LDS, f split into 4 quarters (R2-proven) ----------

__global__ __launch_bounds__(256) void conv2_lds(const float* __restrict__ x1,
                                                 const float* __restrict__ attr2,
                                                 const int* __restrict__ ei2,
                                                 const float* __restrict__ W2,
                                                 float* __restrict__ agg2,
                                                 float* __restrict__ cnt2) {
    __shared__ float wl[25 * 8 * FH * 4];
    const int q = blockIdx.x & 3;
    const int blk = blockIdx.x >> 2;
    const int t = threadIdx.x;

    for (int i = t; i < 25 * 8 * FH * 4; i += 256) {
        int c = i & 3;
        int fh = (i >> 2) & (FH - 1);
        int g = (i >> 6) & 7;
        int s = i >> 9;
        wl[i] = W2[s * 2048 + (g * 4 + c) * 64 + q * FH + fh];
    }
    __syncthreads();

    const int fh = t & (FH - 1);
    const int grp = t >> 4;
    const int EPB = (EE2 + NBLK - 1) / NBLK;
    const int e0 = blk * EPB;
    const int e_end = min(e0 + EPB, EE2);
    const float4* wl4 = (const float4*)wl;

    for (int e = e0 + grp; e < e_end; e += 16) {
        int src = ei2[e], dst = ei2[EE2 + e];
        int idx[4]; float w[4];
        spline_basis(attr2[2 * e], attr2[2 * e + 1], idx, w);
        const float4* xp = (const float4*)(x1 + src * 32);
        float4 xv[8];
#pragma unroll
        for (int g = 0; g < 8; ++g) xv[g] = xp[g];
        float msg = 0.0f;
#pragma unroll
        for (int k = 0; k < 4; ++k) {
            const float4* wp = wl4 + idx[k] * (8 * FH) + fh;
            float acc = 0.0f;
#pragma unroll
            for (int g = 0; g < 8; ++g) {
                float4 wv = wp[g * FH];
                acc += xv[g].x * wv.x;
                acc += xv[g].y * wv.y;
                acc += xv[g].z * wv.z;
                acc += xv[g].w * wv.w;
            }
            msg += w[k] * acc;
        }
        atomicAdd(&agg2[dst * 64 + q * FH + fh], msg);
        if (q == 0 && fh == 0) atomicAdd(&cnt2[dst], 1.0f);
    }
}

// ---------- conv2 finish + pool2 (fused, R5-proven) ----------

__global__ void conv2fin_pool2(const float* __restrict__ x1, const float* __restrict__ root2,
                               const float* __restrict__ bias2, const float* __restrict__ cnt2,
                               const float* __restrict__ agg2, const int* __restrict__ cl2,
                               const int* __restrict__ batch1, unsigned* __restrict__ x2key,
                               int* __restrict__ ccnt2, int* __restrict__ batch2) {
    int gid = blockIdx.x * blockDim.x + threadIdx.x;
    if (gid >= NP1 * 64) return;
    int n = gid >> 6, f = gid & 63;
    float r = 0.0f;
    const float* xs = x1 + n * 32;
#pragma unroll
    for (int i = 0; i < 32; ++i) r += xs[i] * root2[i * 64 + f];
    float v = elu1(agg2[gid] / fmaxf(cnt2[n], 1.0f) + r + bias2[f]);
    int c = cl2[n];
    atomicMax(&x2key[c * 64 + f], fkey(v));
    if (f == 0) {
        atomicAdd(&ccnt2[c], 1);
        atomicMax(&batch2[c], batch1[n]);
    }
}

// ---------- global mean pool: per-block LDS partials, no global atomics ----------

__global__ __launch_bounds__(256) void pool2_part(const unsigned* __restrict__ x2key,
                                                  const int* __restrict__ ccnt2,
                                                  const int* __restrict__ batch2,
                                                  float* __restrict__ partial,
                                                  float* __restrict__ pcnt) {
    __shared__ float gs[GG * 64 + GG];
    const int t = threadIdx.x;
    for (int i = t; i < GG * 64 + GG; i += 256) gs[i] = 0.0f;
    __syncthreads();
    const int lane = t & 63, wv = t >> 6;
    const int c0 = blockIdx.x * CPB2;
    const int c1 = min(c0 + CPB2, NP2);
    for (int c = c0 + wv; c < c1; c += 4) {
        int cnt = ccnt2[c];
        int g = batch2[c];
        float v = cnt > 0 ? fkey_inv(x2key[c * 64 + lane]) : 0.0f;
        atomicAdd(&gs[g * 64 + lane], v);
        if (lane == 0) atomicAdd(&gs[GG * 64 + g], 1.0f);
    }
    __syncthreads();
    float* pb = partial + (size_t)blockIdx.x * (GG * 64);
    for (int i = t; i < GG * 64; i += 256) pb[i] = gs[i];
    if (t < GG) pcnt[blockIdx.x * GG + t] = gs[GG * 64 + t];
}

// ---------- fused partial-reduce + head (one block per graph) ----------

__global__ __launch_bounds__(128) void gpool_head(const float* __restrict__ partial,
                                                  const float* __restrict__ pcnt,
                                                  const float* __restrict__ fc1w,
                                                  const float* __restrict__ fc1b,
                                                  const float* __restrict__ fc2w,
                                                  const float* __restrict__ fc2b,
                                                  float* __restrict__ out) {
    const int g = blockIdx.x;
    const int t = threadIdx.x;  // 128
    __shared__ float red[128];
    __shared__ float acc2[128];
    __shared__ float gm[64];
    __shared__ float h3[128];
    __shared__ float lg[3];

    red[t] = (t < PB2) ? pcnt[t * GG + g] : 0.0f;
    __syncthreads();
    for (int s = 64; s > 0; s >>= 1) {
        if (t < s) red[t] += red[t + s];
        __syncthreads();
    }

    const int f = t & 63, h = t >> 6;
    float acc = 0.0f;
    for (int b = h * (PB2 / 2); b < (h + 1) * (PB2 / 2); ++b)
        acc += partial[(size_t)b * (GG * 64) + g * 64 + f];
    acc2[t] = acc;
    __syncthreads();
    if (t < 64) gm[t] = (acc2[t] + acc2[t + 64]) / fmaxf(red[0], 1.0f);
    __syncthreads();

    float a = fc1b[t];
#pragma unroll
    for (int i = 0; i < 64; ++i) a += gm[i] * fc1w[i * 128 + t];
    h3[t] = elu1(a);
    __syncthreads();
    if (t < 3) {
        float a2 = fc2b[t];
#pragma unroll
        for (int i = 0; i < 128; ++i) a2 += h3[i] * fc2w[i * 3 + t];
        lg[t] = a2;
    }
    __syncthreads();
    if (t == 0) {
        float m = fmaxf(lg[0], fmaxf(lg[1], lg[2]));
        float s = expf(lg[0] - m) + expf(lg[1] - m) + expf(lg[2] - m);
        float lse = m + logf(s);
        out[g * 3 + 0] = lg[0] - lse;
        out[g * 3 + 1] = lg[1] - lse;
        out[g * 3 + 2] = lg[2] - lse;
    }
}

// ---------- launcher ----------

extern "C" void kernel_launch(void* const* d_in, const int* in_sizes, int n_in,
                              void* d_out, int out_size, void* d_ws, size_t ws_size,
                              hipStream_t stream) {
    const float* x     = (const float*)d_in[0];
    const float* pos   = (const float*)d_in[1];
    const float* eattr = (const float*)d_in[2];
    const int*   ei    = (const int*)d_in[3];
    const int*   batch = (const int*)d_in[4];
    const int*   cl1   = (const int*)d_in[5];
    const int*   ei2   = (const int*)d_in[6];
    const int*   cl2   = (const int*)d_in[7];
    const float* W1    = (const float*)d_in[8];
    const float* root1 = (const float*)d_in[9];
    const float* bias1 = (const float*)d_in[10];
    const float* W2    = (const float*)d_in[11];
    const float* root2 = (const float*)d_in[12];
    const float* bias2 = (const float*)d_in[13];
    const float* fc1w  = (const float*)d_in[14];
    const float* fc1b  = (const float*)d_in[15];
    const float* fc2w  = (const float*)d_in[16];
    const float* fc2b  = (const float*)d_in[17];
    float* out = (float*)d_out;

    char* p = (char*)d_ws;
    auto carve = [&](size_t bytes) {
        char* r = p;
        p += (bytes + 255) & ~(size_t)255;
        return r;
    };
    // regions needing zero-init first, fully-overwritten regions after the mark
    float*    agg25   = (float*)carve((size_t)NN * 25 * 4);
    float*    cnt1    = (float*)carve((size_t)NN * 4);
    unsigned* x1key   = (unsigned*)carve((size_t)NP1 * 32 * 4);  // becomes float x1 in-place
    int*      ccnt1   = (int*)carve((size_t)NP1 * 4);
    float*    pos1    = (float*)carve((size_t)NP1 * 2 * 4);
    int*      batch1  = (int*)carve((size_t)NP1 * 4);
    unsigned* scaleb  = (unsigned*)carve(4);
    float*    agg2    = (float*)carve((size_t)NP1 * 64 * 4);
    float*    cnt2    = (float*)carve((size_t)NP1 * 4);
    unsigned* x2key   = (unsigned*)carve((size_t)NP2 * 64 * 4);
    int*      ccnt2   = (int*)carve((size_t)NP2 * 4);
    int*      batch2  = (int*)carve((size_t)NP2 * 4);
    size_t zero_bytes = (size_t)(p - (char*)d_ws);
    float*    attr2   = (float*)carve((size_t)EE2 * 2 * 4);
    float*    partial = (float*)carve((size_t)PB2 * GG * 64 * 4);
    float*    pcnt    = (float*)carve((size_t)PB2 * GG * 4);

    hipMemsetAsync(d_ws, 0, zero_bytes, stream);

    const int B = 256;
    conv1_edge25<<<(EE + B - 1) / B, B, 0, stream>>>(x, eattr, ei, agg25, cnt1);
    conv1gemm_pool1<<<NN / 8, B, 0, stream>>>(x, W1, root1, bias1, cnt1, agg25,
                                              pos, batch, cl1, x1key, ccnt1, pos1, batch1);
    pool1_fin<<<(NP1 * 32 + B - 1) / B, B, 0, stream>>>(x1key, ccnt1, pos1);
    cart_k<<<(EE2 + B - 1) / B, B, 0, stream>>>(pos1, ei2, attr2, scaleb);
    attr2_fin<<<(EE2 * 2 + B - 1) / B, B, 0, stream>>>(attr2, scaleb);
    conv2_lds<<<NBLK * 4, B, 0, stream>>>((const float*)x1key, attr2, ei2, W2, agg2, cnt2);
    conv2fin_pool2<<<(NP1 * 64 + B - 1) / B, B, 0, stream>>>((const float*)x1key, root2, bias2,
                                                             cnt2, agg2, cl2, batch1, x2key,
                                                             ccnt2, batch2);
    pool2_part<<<PB2, B, 0, stream>>>(x2key, ccnt2, batch2, partial, pcnt);
    gpool_head<<<GG, 128, 0, stream>>>(partial, pcnt, fc1w, fc1b, fc2w, fc2b, out);
}

// Round 12
// 266.056 us; speedup vs baseline: 1.3584x; 1.1333x over previous
//
#include <hip/hip_runtime.h>
#include <math.h>

#define KD 5
#define NN 60000
#define EE 360000
#define NP1 30000
#define EE2 180000
#define NP2 15000
#define GG 60

// conv2 tiling (R2-proven)
#define FH 16      // fout quarter width
#define NBLK 512   // edge blocks per quarter

// pool2/global-pool partials
#define PB2 120
#define CPB2 125   // ceil(NP2 / PB2)

// ---------- helpers ----------

__device__ __forceinline__ unsigned fkey(float f) {
    unsigned u = __float_as_uint(f);
    return (u & 0x80000000u) ? ~u : (u | 0x80000000u);
}
__device__ __forceinline__ float fkey_inv(unsigned k) {
    unsigned u = (k & 0x80000000u) ? (k ^ 0x80000000u) : ~k;
    return __uint_as_float(u);
}

__device__ __forceinline__ void spline_basis(float p0, float p1, int* idx, float* w) {
    float v0 = p0 * 4.0f, v1 = p1 * 4.0f;
    float fl0 = floorf(v0), fl1 = floorf(v1);
    int i0 = min(max((int)fl0, 0), KD - 1);
    int i1 = min(max((int)fl1, 0), KD - 1);
    float fr0 = v0 - fl0, fr1 = v1 - fl1;
    int c = 0;
#pragma unroll
    for (int s0 = 0; s0 < 2; ++s0) {
#pragma unroll
        for (int s1 = 0; s1 < 2; ++s1) {
            int ix = min(i0 + s0, KD - 1);
            int iy = min(i1 + s1, KD - 1);
            float w0 = s0 ? fr0 : 1.0f - fr0;
            float w1 = s1 ? fr1 : 1.0f - fr1;
            idx[c] = ix + KD * iy;
            w[c] = w0 * w1;
            ++c;
        }
    }
}

__device__ __forceinline__ float elu1(float v) {
    return v > 0.0f ? v : expm1f(v);
}

// ---------- conv1 (R3-proven 32-lane edge kernel) ----------

__global__ void conv1_edge(const float* __restrict__ x, const float* __restrict__ ea,
                           const int* __restrict__ ei, const float* __restrict__ W1,
                           float* __restrict__ agg1, float* __restrict__ cnt1) {
    int gid = blockIdx.x * blockDim.x + threadIdx.x;
    if (gid >= EE * 32) return;
    int e = gid >> 5, f = gid & 31;
    int src = ei[e], dst = ei[EE + e];
    int idx[4]; float w[4];
    spline_basis(ea[2 * e], ea[2 * e + 1], idx, w);
    float coeff = 0.0f;
#pragma unroll
    for (int k = 0; k < 4; ++k) coeff += w[k] * W1[idx[k] * 32 + f];
    atomicAdd(&agg1[dst * 32 + f], x[src] * coeff);
    if (f == 0) atomicAdd(&cnt1[dst], 1.0f);
}

// ---------- conv1 finish + pool1 (fused, R5-proven) ----------

__global__ void conv1fin_pool1(const float* __restrict__ x, const float* __restrict__ root1,
                               const float* __restrict__ bias1, const float* __restrict__ cnt1,
                               const float* __restrict__ agg1, const float* __restrict__ pos,
                               const int* __restrict__ batch, const int* __restrict__ cl1,
                               unsigned* __restrict__ x1key, int* __restrict__ ccnt1,
                               float* __restrict__ pos1, int* __restrict__ batch1) {
    int gid = blockIdx.x * blockDim.x + threadIdx.x;
    if (gid >= NN * 32) return;
    int n = gid >> 5, f = gid & 31;
    float v = elu1(agg1[gid] / fmaxf(cnt1[n], 1.0f) + x[n] * root1[f] + bias1[f]);
    int c = cl1[n];
    atomicMax(&x1key[c * 32 + f], fkey(v));
    if (f == 0) {
        atomicAdd(&ccnt1[c], 1);
        atomicAdd(&pos1[c * 2], pos[n * 2]);
        atomicAdd(&pos1[c * 2 + 1], pos[n * 2 + 1]);
        atomicMax(&batch1[c], batch[n]);
    }
}

__global__ void pool1_fin(unsigned* __restrict__ x1key, const int* __restrict__ ccnt1,
                          float* __restrict__ pos1) {
    int gid = blockIdx.x * blockDim.x + threadIdx.x;
    if (gid >= NP1 * 32) return;
    int c = gid >> 5, f = gid & 31;
    int cnt = ccnt1[c];
    float v = cnt > 0 ? fkey_inv(x1key[gid]) : 0.0f;
    ((float*)x1key)[gid] = v;
    if (f < 2) pos1[c * 2 + f] = pos1[c * 2 + f] / fmaxf((float)cnt, 1.0f);
}

// ---------- cartesian ----------

__global__ void cart_k(const float* __restrict__ pos1, const int* __restrict__ ei2,
                       float* __restrict__ attr2, unsigned* __restrict__ scaleb) {
    int e = blockIdx.x * blockDim.x + threadIdx.x;
    float m = 0.0f;
    if (e < EE2) {
        int s = ei2[e], d = ei2[EE2 + e];
        float c0 = pos1[d * 2] - pos1[s * 2];
        float c1 = pos1[d * 2 + 1] - pos1[s * 2 + 1];
        attr2[e * 2] = c0;
        attr2[e * 2 + 1] = c1;
        m = fmaxf(fabsf(c0), fabsf(c1));
    }
#pragma unroll
    for (int off = 32; off > 0; off >>= 1) m = fmaxf(m, __shfl_down(m, off));
    if ((threadIdx.x & 63) == 0) atomicMax(scaleb, __float_as_uint(m));
}

__global__ void attr2_fin(float* __restrict__ attr2, const unsigned* __restrict__ scaleb) {
    int gid = blockIdx.x * blockDim.x + threadIdx.x;
    if (gid >= EE2 * 2) return;
    float s = fmaxf(__uint_as_float(*scaleb), 1e-12f);
    attr2[gid] = attr2[gid] / (2.0f * s) + 0.5f;
}

// ---------- conv2: W2 staged in LDS, f split into 4 quarters (R2-proven) ----------

__global__ __launch_bounds__(256) void conv2_lds(const float* __restrict__ x1,
                                                 const float* __restrict__ attr2,
                                                 const int* __restrict__ ei2,
                                                 const float* __restrict__ W2,
                                                 float* __restrict__ agg2,
                                                 float* __restrict__ cnt2) {
    __shared__ float wl[25 * 8 * FH * 4];
    const int q = blockIdx.x & 3;
    const int blk = blockIdx.x >> 2;
    const int t = threadIdx.x;

    for (int i = t; i < 25 * 8 * FH * 4; i += 256) {
        int c = i & 3;
        int fh = (i >> 2) & (FH - 1);
        int g = (i >> 6) & 7;
        int s = i >> 9;
        wl[i] = W2[s * 2048 + (g * 4 + c) * 64 + q * FH + fh];
    }
    __syncthreads();

    const int fh = t & (FH - 1);
    const int grp = t >> 4;
    const int EPB = (EE2 + NBLK - 1) / NBLK;
    const int e0 = blk * EPB;
    const int e_end = min(e0 + EPB, EE2);
    const float4* wl4 = (const float4*)wl;

    for (int e = e0 + grp; e < e_end; e += 16) {
        int src = ei2[e], dst = ei2[EE2 + e];
        int idx[4]; float w[4];
        spline_basis(attr2[2 * e], attr2[2 * e + 1], idx, w);
        const float4* xp = (const float4*)(x1 + src * 32);
        float4 xv[8];
#pragma unroll
        for (int g = 0; g < 8; ++g) xv[g] = xp[g];
        float msg = 0.0f;
#pragma unroll
        for (int k = 0; k < 4; ++k) {
            const float4* wp = wl4 + idx[k] * (8 * FH) + fh;
            float acc = 0.0f;
#pragma unroll
            for (int g = 0; g < 8; ++g) {
                float4 wv = wp[g * FH];
                acc += xv[g].x * wv.x;
                acc += xv[g].y * wv.y;
                acc += xv[g].z * wv.z;
                acc += xv[g].w * wv.w;
            }
            msg += w[k] * acc;
        }
        atomicAdd(&agg2[dst * 64 + q * FH + fh], msg);
        if (q == 0 && fh == 0) atomicAdd(&cnt2[dst], 1.0f);
    }
}

// ---------- conv2 finish + pool2 (fused, R5-proven) ----------

__global__ void conv2fin_pool2(const float* __restrict__ x1, const float* __restrict__ root2,
                               const float* __restrict__ bias2, const float* __restrict__ cnt2,
                               const float* __restrict__ agg2, const int* __restrict__ cl2,
                               const int* __restrict__ batch1, unsigned* __restrict__ x2key,
                               int* __restrict__ ccnt2, int* __restrict__ batch2) {
    int gid = blockIdx.x * blockDim.x + threadIdx.x;
    if (gid >= NP1 * 64) return;
    int n = gid >> 6, f = gid & 63;
    float r = 0.0f;
    const float* xs = x1 + n * 32;
#pragma unroll
    for (int i = 0; i < 32; ++i) r += xs[i] * root2[i * 64 + f];
    float v = elu1(agg2[gid] / fmaxf(cnt2[n], 1.0f) + r + bias2[f]);
    int c = cl2[n];
    atomicMax(&x2key[c * 64 + f], fkey(v));
    if (f == 0) {
        atomicAdd(&ccnt2[c], 1);
        atomicMax(&batch2[c], batch1[n]);
    }
}

// ---------- global mean pool: per-block LDS partials, no global atomics ----------

__global__ __launch_bounds__(256) void pool2_part(const unsigned* __restrict__ x2key,
                                                  const int* __restrict__ ccnt2,
                                                  const int* __restrict__ batch2,
                                                  float* __restrict__ partial,
                                                  float* __restrict__ pcnt) {
    __shared__ float gs[GG * 64 + GG];
    const int t = threadIdx.x;
    for (int i = t; i < GG * 64 + GG; i += 256) gs[i] = 0.0f;
    __syncthreads();
    const int lane = t & 63, wv = t >> 6;
    const int c0 = blockIdx.x * CPB2;
    const int c1 = min(c0 + CPB2, NP2);
    for (int c = c0 + wv; c < c1; c += 4) {
        int cnt = ccnt2[c];
        int g = batch2[c];
        float v = cnt > 0 ? fkey_inv(x2key[c * 64 + lane]) : 0.0f;
        atomicAdd(&gs[g * 64 + lane], v);
        if (lane == 0) atomicAdd(&gs[GG * 64 + g], 1.0f);
    }
    __syncthreads();
    float* pb = partial + (size_t)blockIdx.x * (GG * 64);
    for (int i = t; i < GG * 64; i += 256) pb[i] = gs[i];
    if (t < GG) pcnt[blockIdx.x * GG + t] = gs[GG * 64 + t];
}

// ---------- fused partial-reduce + head (one block per graph) ----------

__global__ __launch_bounds__(128) void gpool_head(const float* __restrict__ partial,
                                                  const float* __restrict__ pcnt,
                                                  const float* __restrict__ fc1w,
                                                  const float* __restrict__ fc1b,
                                                  const float* __restrict__ fc2w,
                                                  const float* __restrict__ fc2b,
                                                  float* __restrict__ out) {
    const int g = blockIdx.x;
    const int t = threadIdx.x;  // 128
    __shared__ float red[128];
    __shared__ float acc2[128];
    __shared__ float gm[64];
    __shared__ float h3[128];
    __shared__ float lg[3];

    red[t] = (t < PB2) ? pcnt[t * GG + g] : 0.0f;
    __syncthreads();
    for (int s = 64; s > 0; s >>= 1) {
        if (t < s) red[t] += red[t + s];
        __syncthreads();
    }

    const int f = t & 63, h = t >> 6;
    float acc = 0.0f;
    for (int b = h * (PB2 / 2); b < (h + 1) * (PB2 / 2); ++b)
        acc += partial[(size_t)b * (GG * 64) + g * 64 + f];
    acc2[t] = acc;
    __syncthreads();
    if (t < 64) gm[t] = (acc2[t] + acc2[t + 64]) / fmaxf(red[0], 1.0f);
    __syncthreads();

    float a = fc1b[t];
#pragma unroll
    for (int i = 0; i < 64; ++i) a += gm[i] * fc1w[i * 128 + t];
    h3[t] = elu1(a);
    __syncthreads();
    if (t < 3) {
        float a2 = fc2b[t];
#pragma unroll
        for (int i = 0; i < 128; ++i) a2 += h3[i] * fc2w[i * 3 + t];
        lg[t] = a2;
    }
    __syncthreads();
    if (t == 0) {
        float m = fmaxf(lg[0], fmaxf(lg[1], lg[2]));
        float s = expf(lg[0] - m) + expf(lg[1] - m) + expf(lg[2] - m);
        float lse = m + logf(s);
        out[g * 3 + 0] = lg[0] - lse;
        out[g * 3 + 1] = lg[1] - lse;
        out[g * 3 + 2] = lg[2] - lse;
    }
}

// ---------- launcher ----------

extern "C" void kernel_launch(void* const* d_in, const int* in_sizes, int n_in,
                              void* d_out, int out_size, void* d_ws, size_t ws_size,
                              hipStream_t stream) {
    const float* x     = (const float*)d_in[0];
    const float* pos   = (const float*)d_in[1];
    const float* eattr = (const float*)d_in[2];
    const int*   ei    = (const int*)d_in[3];
    const int*   batch = (const int*)d_in[4];
    const int*   cl1   = (const int*)d_in[5];
    const int*   ei2   = (const int*)d_in[6];
    const int*   cl2   = (const int*)d_in[7];
    const float* W1    = (const float*)d_in[8];
    const float* root1 = (const float*)d_in[9];
    const float* bias1 = (const float*)d_in[10];
    const float* W2    = (const float*)d_in[11];
    const float* root2 = (const float*)d_in[12];
    const float* bias2 = (const float*)d_in[13];
    const float* fc1w  = (const float*)d_in[14];
    const float* fc1b  = (const float*)d_in[15];
    const float* fc2w  = (const float*)d_in[16];
    const float* fc2b  = (const float*)d_in[17];
    float* out = (float*)d_out;

    char* p = (char*)d_ws;
    auto carve = [&](size_t bytes) {
        char* r = p;
        p += (bytes + 255) & ~(size_t)255;
        return r;
    };
    // regions needing zero-init first, fully-overwritten regions after the mark
    float*    agg1    = (float*)carve((size_t)NN * 32 * 4);
    float*    cnt1    = (float*)carve((size_t)NN * 4);
    unsigned* x1key   = (unsigned*)carve((size_t)NP1 * 32 * 4);  // becomes float x1 in-place
    int*      ccnt1   = (int*)carve((size_t)NP1 * 4);
    float*    pos1    = (float*)carve((size_t)NP1 * 2 * 4);
    int*      batch1  = (int*)carve((size_t)NP1 * 4);
    unsigned* scaleb  = (unsigned*)carve(4);
    float*    agg2    = (float*)carve((size_t)NP1 * 64 * 4);
    float*    cnt2    = (float*)carve((size_t)NP1 * 4);
    unsigned* x2key   = (unsigned*)carve((size_t)NP2 * 64 * 4);
    int*      ccnt2   = (int*)carve((size_t)NP2 * 4);
    int*      batch2  = (int*)carve((size_t)NP2 * 4);
    size_t zero_bytes = (size_t)(p - (char*)d_ws);
    float*    attr2   = (float*)carve((size_t)EE2 * 2 * 4);
    float*    partial = (float*)carve((size_t)PB2 * GG * 64 * 4);
    float*    pcnt    = (float*)carve((size_t)PB2 * GG * 4);

    hipMemsetAsync(d_ws, 0, zero_bytes, stream);

    const int B = 256;
    conv1_edge<<<(EE * 32 + B - 1) / B, B, 0, stream>>>(x, eattr, ei, W1, agg1, cnt1);
    conv1fin_pool1<<<(NN * 32 + B - 1) / B, B, 0, stream>>>(x, root1, bias1, cnt1, agg1,
                                                            pos, batch, cl1, x1key, ccnt1,
                                                            pos1, batch1);
    pool1_fin<<<(NP1 * 32 + B - 1) / B, B, 0, stream>>>(x1key, ccnt1, pos1);
    cart_k<<<(EE2 + B - 1) / B, B, 0, stream>>>(pos1, ei2, attr2, scaleb);
    attr2_fin<<<(EE2 * 2 + B - 1) / B, B, 0, stream>>>(attr2, scaleb);
    conv2_lds<<<NBLK * 4, B, 0, stream>>>((const float*)x1key, attr2, ei2, W2, agg2, cnt2);
    conv2fin_pool2<<<(NP1 * 64 + B - 1) / B, B, 0, stream>>>((const float*)x1key, root2, bias2,
                                                             cnt2, agg2, cl2, batch1, x2key,
                                                             ccnt2, batch2);
    pool2_part<<<PB2, B, 0, stream>>>(x2key, ccnt2, batch2, partial, pcnt);
    gpool_head<<<GG, 128, 0, stream>>>(partial, pcnt, fc1w, fc1b, fc2w, fc2b, out);
}

// Round 13
// 250.695 us; speedup vs baseline: 1.4417x; 1.0613x over previous
//
#include <hip/hip_runtime.h>
#include <math.h>

#define KD 5
#define NN 60000
#define EE 360000
#define NP1 30000
#define EE2 180000
#define NP2 15000
#define GG 60

// conv2 tiling (R2-proven structure, f16 weights)
#define FH 16      // fout quarter width
#define NBLK 512   // edge blocks per quarter

// pool2/global-pool partials
#define PB2 120
#define CPB2 125   // ceil(NP2 / PB2)

typedef _Float16 h2 __attribute__((ext_vector_type(2)));

__device__ __forceinline__ float dot2h(unsigned w, unsigned x, float c) {
    return __builtin_amdgcn_fdot2(__builtin_bit_cast(h2, w),
                                  __builtin_bit_cast(h2, x), c, false);
}

// ---------- helpers ----------

__device__ __forceinline__ unsigned fkey(float f) {
    unsigned u = __float_as_uint(f);
    return (u & 0x80000000u) ? ~u : (u | 0x80000000u);
}
__device__ __forceinline__ float fkey_inv(unsigned k) {
    unsigned u = (k & 0x80000000u) ? (k ^ 0x80000000u) : ~k;
    return __uint_as_float(u);
}

__device__ __forceinline__ void spline_basis(float p0, float p1, int* idx, float* w) {
    float v0 = p0 * 4.0f, v1 = p1 * 4.0f;
    float fl0 = floorf(v0), fl1 = floorf(v1);
    int i0 = min(max((int)fl0, 0), KD - 1);
    int i1 = min(max((int)fl1, 0), KD - 1);
    float fr0 = v0 - fl0, fr1 = v1 - fl1;
    int c = 0;
#pragma unroll
    for (int s0 = 0; s0 < 2; ++s0) {
#pragma unroll
        for (int s1 = 0; s1 < 2; ++s1) {
            int ix = min(i0 + s0, KD - 1);
            int iy = min(i1 + s1, KD - 1);
            float w0 = s0 ? fr0 : 1.0f - fr0;
            float w1 = s1 ? fr1 : 1.0f - fr1;
            idx[c] = ix + KD * iy;
            w[c] = w0 * w1;
            ++c;
        }
    }
}

__device__ __forceinline__ float elu1(float v) {
    return v > 0.0f ? v : expm1f(v);
}

// ---------- conv1 (R3-proven 32-lane edge kernel) ----------

__global__ void conv1_edge(const float* __restrict__ x, const float* __restrict__ ea,
                           const int* __restrict__ ei, const float* __restrict__ W1,
                           float* __restrict__ agg1, float* __restrict__ cnt1) {
    int gid = blockIdx.x * blockDim.x + threadIdx.x;
    if (gid >= EE * 32) return;
    int e = gid >> 5, f = gid & 31;
    int src = ei[e], dst = ei[EE + e];
    int idx[4]; float w[4];
    spline_basis(ea[2 * e], ea[2 * e + 1], idx, w);
    float coeff = 0.0f;
#pragma unroll
    for (int k = 0; k < 4; ++k) coeff += w[k] * W1[idx[k] * 32 + f];
    atomicAdd(&agg1[dst * 32 + f], x[src] * coeff);
    if (f == 0) atomicAdd(&cnt1[dst], 1.0f);
}

// ---------- conv1 finish + pool1 (fused, R5-proven) ----------

__global__ void conv1fin_pool1(const float* __restrict__ x, const float* __restrict__ root1,
                               const float* __restrict__ bias1, const float* __restrict__ cnt1,
                               const float* __restrict__ agg1, const float* __restrict__ pos,
                               const int* __restrict__ batch, const int* __restrict__ cl1,
                               unsigned* __restrict__ x1key, int* __restrict__ ccnt1,
                               float* __restrict__ pos1, int* __restrict__ batch1) {
    int gid = blockIdx.x * blockDim.x + threadIdx.x;
    if (gid >= NN * 32) return;
    int n = gid >> 5, f = gid & 31;
    float v = elu1(agg1[gid] / fmaxf(cnt1[n], 1.0f) + x[n] * root1[f] + bias1[f]);
    int c = cl1[n];
    atomicMax(&x1key[c * 32 + f], fkey(v));
    if (f == 0) {
        atomicAdd(&ccnt1[c], 1);
        atomicAdd(&pos1[c * 2], pos[n * 2]);
        atomicAdd(&pos1[c * 2 + 1], pos[n * 2 + 1]);
        atomicMax(&batch1[c], batch[n]);
    }
}

// pool1 finish: also emits x1 packed as half2 pairs for the f16 conv2
__global__ void pool1_fin(unsigned* __restrict__ x1key, const int* __restrict__ ccnt1,
                          float* __restrict__ pos1, unsigned* __restrict__ x1h) {
    int gid = blockIdx.x * blockDim.x + threadIdx.x;
    if (gid >= NP1 * 32) return;
    int c = gid >> 5, f = gid & 31;
    int cnt = ccnt1[c];
    float v = cnt > 0 ? fkey_inv(x1key[gid]) : 0.0f;
    ((float*)x1key)[gid] = v;
    float vn = __shfl_xor(v, 1);           // neighbor f^1 (adjacent lane)
    if ((f & 1) == 0)
        x1h[c * 16 + (f >> 1)] = __builtin_bit_cast(unsigned,
                                     __builtin_amdgcn_cvt_pkrtz(v, vn));
    if (f < 2) pos1[c * 2 + f] = pos1[c * 2 + f] / fmaxf((float)cnt, 1.0f);
}

// ---------- cartesian (raw cart stored; scale applied inline downstream) ----------

__global__ void cart_k(const float* __restrict__ pos1, const int* __restrict__ ei2,
                       float* __restrict__ cart, unsigned* __restrict__ scaleb) {
    int e = blockIdx.x * blockDim.x + threadIdx.x;
    float m = 0.0f;
    if (e < EE2) {
        int s = ei2[e], d = ei2[EE2 + e];
        float c0 = pos1[d * 2] - pos1[s * 2];
        float c1 = pos1[d * 2 + 1] - pos1[s * 2 + 1];
        cart[e * 2] = c0;
        cart[e * 2 + 1] = c1;
        m = fmaxf(fabsf(c0), fabsf(c1));
    }
#pragma unroll
    for (int off = 32; off > 0; off >>= 1) m = fmaxf(m, __shfl_down(m, off));
    if ((threadIdx.x & 63) == 0) atomicMax(scaleb, __float_as_uint(m));
}

// ---------- conv2: W2 as half2 in LDS (25.6KB), v_dot2_f32_f16 inner loop ----------
// LDS layout: uint4 unit u = (slot*4+gg)*16 + fh  holds fi = gg*8..gg*8+7 at
// fout = q*16+fh, packed as 4x half2. Per edge-thread: 16 ds_read_b128 +
// 4 global b128 (x1h) + 64 dot2 -> both LDS and VALU pipes halved vs fp32.

__global__ __launch_bounds__(256) void conv2_f16(const unsigned* __restrict__ x1h,
                                                 const float* __restrict__ cart,
                                                 const int* __restrict__ ei2,
                                                 const unsigned* __restrict__ scaleb,
                                                 const float* __restrict__ W2,
                                                 float* __restrict__ agg2,
                                                 float* __restrict__ cnt2) {
    __shared__ unsigned wl[25 * 4 * 16 * 4];   // 6400 half2 units = 25.6KB
    const int q = blockIdx.x & 3;
    const int blk = blockIdx.x >> 2;
    const int t = threadIdx.x;

    for (int i = t; i < 6400; i += 256) {
        int pp = i & 3;
        int fh = (i >> 2) & 15;
        int gg = (i >> 6) & 3;
        int s  = i >> 8;
        int fi = gg * 8 + pp * 2;
        int fo = q * FH + fh;
        float w0 = W2[s * 2048 + fi * 64 + fo];
        float w1 = W2[s * 2048 + (fi + 1) * 64 + fo];
        wl[i] = __builtin_bit_cast(unsigned, __builtin_amdgcn_cvt_pkrtz(w0, w1));
    }
    __syncthreads();

    const float sc = fmaxf(__uint_as_float(*scaleb), 1e-12f);
    const int fh = t & (FH - 1);
    const int grp = t >> 4;
    const int EPB = (EE2 + NBLK - 1) / NBLK;
    const int e0 = blk * EPB;
    const int e_end = min(e0 + EPB, EE2);
    const uint4* wl4 = (const uint4*)wl;

    for (int e = e0 + grp; e < e_end; e += 16) {
        int src = ei2[e], dst = ei2[EE2 + e];
        float p0 = cart[2 * e] / (2.0f * sc) + 0.5f;
        float p1 = cart[2 * e + 1] / (2.0f * sc) + 0.5f;
        int idx[4]; float w[4];
        spline_basis(p0, p1, idx, w);
        const uint4* xp = (const uint4*)(x1h + src * 16);
        uint4 xq[4];
#pragma unroll
        for (int gg = 0; gg < 4; ++gg) xq[gg] = xp[gg];
        float msg = 0.0f;
#pragma unroll
        for (int k = 0; k < 4; ++k) {
            float acc = 0.0f;
#pragma unroll
            for (int gg = 0; gg < 4; ++gg) {
                uint4 wv = wl4[idx[k] * 64 + gg * 16 + fh];
                acc = dot2h(wv.x, xq[gg].x, acc);
                acc = dot2h(wv.y, xq[gg].y, acc);
                acc = dot2h(wv.z, xq[gg].z, acc);
                acc = dot2h(wv.w, xq[gg].w, acc);
            }
            msg += w[k] * acc;
        }
        atomicAdd(&agg2[dst * 64 + q * FH + fh], msg);
        if (q == 0 && fh == 0) atomicAdd(&cnt2[dst], 1.0f);
    }
}

// ---------- conv2 finish + pool2 (fused, R5-proven; root term stays fp32) ----------

__global__ void conv2fin_pool2(const float* __restrict__ x1, const float* __restrict__ root2,
                               const float* __restrict__ bias2, const float* __restrict__ cnt2,
                               const float* __restrict__ agg2, const int* __restrict__ cl2,
                               const int* __restrict__ batch1, unsigned* __restrict__ x2key,
                               int* __restrict__ ccnt2, int* __restrict__ batch2) {
    int gid = blockIdx.x * blockDim.x + threadIdx.x;
    if (gid >= NP1 * 64) return;
    int n = gid >> 6, f = gid & 63;
    float r = 0.0f;
    const float* xs = x1 + n * 32;
#pragma unroll
    for (int i = 0; i < 32; ++i) r += xs[i] * root2[i * 64 + f];
    float v = elu1(agg2[gid] / fmaxf(cnt2[n], 1.0f) + r + bias2[f]);
    int c = cl2[n];
    atomicMax(&x2key[c * 64 + f], fkey(v));
    if (f == 0) {
        atomicAdd(&ccnt2[c], 1);
        atomicMax(&batch2[c], batch1[n]);
    }
}

// ---------- global mean pool: per-block LDS partials, no global atomics ----------

__global__ __launch_bounds__(256) void pool2_part(const unsigned* __restrict__ x2key,
                                                  const int* __restrict__ ccnt2,
                                                  const int* __restrict__ batch2,
                                                  float* __restrict__ partial,
                                                  float* __restrict__ pcnt) {
    __shared__ float gs[GG * 64 + GG];
    const int t = threadIdx.x;
    for (int i = t; i < GG * 64 + GG; i += 256) gs[i] = 0.0f;
    __syncthreads();
    const int lane = t & 63, wv = t >> 6;
    const int c0 = blockIdx.x * CPB2;
    const int c1 = min(c0 + CPB2, NP2);
    for (int c = c0 + wv; c < c1; c += 4) {
        int cnt = ccnt2[c];
        int g = batch2[c];
        float v = cnt > 0 ? fkey_inv(x2key[c * 64 + lane]) : 0.0f;
        atomicAdd(&gs[g * 64 + lane], v);
        if (lane == 0) atomicAdd(&gs[GG * 64 + g], 1.0f);
    }
    __syncthreads();
    float* pb = partial + (size_t)blockIdx.x * (GG * 64);
    for (int i = t; i < GG * 64; i += 256) pb[i] = gs[i];
    if (t < GG) pcnt[blockIdx.x * GG + t] = gs[GG * 64 + t];
}

// ---------- fused partial-reduce + head (one block per graph) ----------

__global__ __launch_bounds__(128) void gpool_head(const float* __restrict__ partial,
                                                  const float* __restrict__ pcnt,
                                                  const float* __restrict__ fc1w,
                                                  const float* __restrict__ fc1b,
                                                  const float* __restrict__ fc2w,
                                                  const float* __restrict__ fc2b,
                                                  float* __restrict__ out) {
    const int g = blockIdx.x;
    const int t = threadIdx.x;  // 128
    __shared__ float red[128];
    __shared__ float acc2[128];
    __shared__ float gm[64];
    __shared__ float h3[128];
    __shared__ float lg[3];

    red[t] = (t < PB2) ? pcnt[t * GG + g] : 0.0f;
    __syncthreads();
    for (int s = 64; s > 0; s >>= 1) {
        if (t < s) red[t] += red[t + s];
        __syncthreads();
    }

    const int f = t & 63, h = t >> 6;
    float acc = 0.0f;
    for (int b = h * (PB2 / 2); b < (h + 1) * (PB2 / 2); ++b)
        acc += partial[(size_t)b * (GG * 64) + g * 64 + f];
    acc2[t] = acc;
    __syncthreads();
    if (t < 64) gm[t] = (acc2[t] + acc2[t + 64]) / fmaxf(red[0], 1.0f);
    __syncthreads();

    float a = fc1b[t];
#pragma unroll
    for (int i = 0; i < 64; ++i) a += gm[i] * fc1w[i * 128 + t];
    h3[t] = elu1(a);
    __syncthreads();
    if (t < 3) {
        float a2 = fc2b[t];
#pragma unroll
        for (int i = 0; i < 128; ++i) a2 += h3[i] * fc2w[i * 3 + t];
        lg[t] = a2;
    }
    __syncthreads();
    if (t == 0) {
        float m = fmaxf(lg[0], fmaxf(lg[1], lg[2]));
        float s = expf(lg[0] - m) + expf(lg[1] - m) + expf(lg[2] - m);
        float lse = m + logf(s);
        out[g * 3 + 0] = lg[0] - lse;
        out[g * 3 + 1] = lg[1] - lse;
        out[g * 3 + 2] = lg[2] - lse;
    }
}

// ---------- launcher ----------

extern "C" void kernel_launch(void* const* d_in, const int* in_sizes, int n_in,
                              void* d_out, int out_size, void* d_ws, size_t ws_size,
                              hipStream_t stream) {
    const float* x     = (const float*)d_in[0];
    const float* pos   = (const float*)d_in[1];
    const float* eattr = (const float*)d_in[2];
    const int*   ei    = (const int*)d_in[3];
    const int*   batch = (const int*)d_in[4];
    const int*   cl1   = (const int*)d_in[5];
    const int*   ei2   = (const int*)d_in[6];
    const int*   cl2   = (const int*)d_in[7];
    const float* W1    = (const float*)d_in[8];
    const float* root1 = (const float*)d_in[9];
    const float* bias1 = (const float*)d_in[10];
    const float* W2    = (const float*)d_in[11];
    const float* root2 = (const float*)d_in[12];
    const float* bias2 = (const float*)d_in[13];
    const float* fc1w  = (const float*)d_in[14];
    const float* fc1b  = (const float*)d_in[15];
    const float* fc2w  = (const float*)d_in[16];
    const float* fc2b  = (const float*)d_in[17];
    float* out = (float*)d_out;

    char* p = (char*)d_ws;
    auto carve = [&](size_t bytes) {
        char* r = p;
        p += (bytes + 255) & ~(size_t)255;
        return r;
    };
    // regions needing zero-init first, fully-overwritten regions after the mark
    float*    agg1    = (float*)carve((size_t)NN * 32 * 4);
    float*    cnt1    = (float*)carve((size_t)NN * 4);
    unsigned* x1key   = (unsigned*)carve((size_t)NP1 * 32 * 4);  // becomes float x1 in-place
    int*      ccnt1   = (int*)carve((size_t)NP1 * 4);
    float*    pos1    = (float*)carve((size_t)NP1 * 2 * 4);
    int*      batch1  = (int*)carve((size_t)NP1 * 4);
    unsigned* scaleb  = (unsigned*)carve(4);
    float*    agg2    = (float*)carve((size_t)NP1 * 64 * 4);
    float*    cnt2    = (float*)carve((size_t)NP1 * 4);
    unsigned* x2key   = (unsigned*)carve((size_t)NP2 * 64 * 4);
    int*      ccnt2   = (int*)carve((size_t)NP2 * 4);
    int*      batch2  = (int*)carve((size_t)NP2 * 4);
    size_t zero_bytes = (size_t)(p - (char*)d_ws);
    unsigned* x1h     = (unsigned*)carve((size_t)NP1 * 16 * 4);  // half2-packed x1
    float*    cart    = (float*)carve((size_t)EE2 * 2 * 4);
    float*    partial = (float*)carve((size_t)PB2 * GG * 64 * 4);
    float*    pcnt    = (float*)carve((size_t)PB2 * GG * 4);

    hipMemsetAsync(d_ws, 0, zero_bytes, stream);

    const int B = 256;
    conv1_edge<<<(EE * 32 + B - 1) / B, B, 0, stream>>>(x, eattr, ei, W1, agg1, cnt1);
    conv1fin_pool1<<<(NN * 32 + B - 1) / B, B, 0, stream>>>(x, root1, bias1, cnt1, agg1,
                                                            pos, batch, cl1, x1key, ccnt1,
                                                            pos1, batch1);
    pool1_fin<<<(NP1 * 32 + B - 1) / B, B, 0, stream>>>(x1key, ccnt1, pos1, x1h);
    cart_k<<<(EE2 + B - 1) / B, B, 0, stream>>>(pos1, ei2, cart, scaleb);
    conv2_f16<<<NBLK * 4, B, 0, stream>>>(x1h, cart, ei2, scaleb, W2, agg2, cnt2);
    conv2fin_pool2<<<(NP1 * 64 + B - 1) / B, B, 0, stream>>>((const float*)x1key, root2, bias2,
                                                             cnt2, agg2, cl2, batch1, x2key,
                                                             ccnt2, batch2);
    pool2_part<<<PB2, B, 0, stream>>>(x2key, ccnt2, batch2, partial, pcnt);
    gpool_head<<<GG, 128, 0, stream>>>(partial, pcnt, fc1w, fc1b, fc2w, fc2b, out);
}

// Round 15
// 230.510 us; speedup vs baseline: 1.5679x; 1.0876x over previous
//
#include <hip/hip_runtime.h>
#include <hip/hip_fp16.h>
#include <math.h>

#define KD 5
#define NN 60000
#define EE 360000
#define NP1 30000
#define EE2 180000
#define NP2 15000
#define GG 60

// conv2 tiling (R2-proven structure, f16 weights)
#define FH 16      // fout quarter width
#define NBLK 512   // edge blocks per quarter

// pool2/global-pool partials
#define PB2 120
#define CPB2 125   // ceil(NP2 / PB2)

typedef _Float16 h2 __attribute__((ext_vector_type(2)));

__device__ __forceinline__ float dot2h(unsigned w, unsigned x, float c) {
    return __builtin_amdgcn_fdot2(__builtin_bit_cast(h2, w),
                                  __builtin_bit_cast(h2, x), c, false);
}

// packed f16x2 atomic add via ISA (no HIP overload for __half2 in ROCm 7.2)
__device__ __forceinline__ void pk_atomic_add(void* addr, unsigned val) {
    asm volatile("global_atomic_pk_add_f16 %0, %1, off"
                 :: "v"(addr), "v"(val) : "memory");
}

// ---------- helpers ----------

__device__ __forceinline__ unsigned fkey(float f) {
    unsigned u = __float_as_uint(f);
    return (u & 0x80000000u) ? ~u : (u | 0x80000000u);
}
__device__ __forceinline__ float fkey_inv(unsigned k) {
    unsigned u = (k & 0x80000000u) ? (k ^ 0x80000000u) : ~k;
    return __uint_as_float(u);
}

__device__ __forceinline__ void spline_basis(float p0, float p1, int* idx, float* w) {
    float v0 = p0 * 4.0f, v1 = p1 * 4.0f;
    float fl0 = floorf(v0), fl1 = floorf(v1);
    int i0 = min(max((int)fl0, 0), KD - 1);
    int i1 = min(max((int)fl1, 0), KD - 1);
    float fr0 = v0 - fl0, fr1 = v1 - fl1;
    int c = 0;
#pragma unroll
    for (int s0 = 0; s0 < 2; ++s0) {
#pragma unroll
        for (int s1 = 0; s1 < 2; ++s1) {
            int ix = min(i0 + s0, KD - 1);
            int iy = min(i1 + s1, KD - 1);
            float w0 = s0 ? fr0 : 1.0f - fr0;
            float w1 = s1 ? fr1 : 1.0f - fr1;
            idx[c] = ix + KD * iy;
            w[c] = w0 * w1;
            ++c;
        }
    }
}

__device__ __forceinline__ float elu1(float v) {
    return v > 0.0f ? v : expm1f(v);
}

// ---------- conv1: 32 lanes/edge, packed-f16 atomics (16 pk-atomics/edge) ----------

__global__ void conv1_edge(const float* __restrict__ x, const float* __restrict__ ea,
                           const int* __restrict__ ei, const float* __restrict__ W1,
                           __half2* __restrict__ agg1h, float* __restrict__ cnt1) {
    int gid = blockIdx.x * blockDim.x + threadIdx.x;
    if (gid >= EE * 32) return;
    int e = gid >> 5, f = gid & 31;
    int src = ei[e], dst = ei[EE + e];
    int idx[4]; float w[4];
    spline_basis(ea[2 * e], ea[2 * e + 1], idx, w);
    float coeff = 0.0f;
#pragma unroll
    for (int k = 0; k < 4; ++k) coeff += w[k] * W1[idx[k] * 32 + f];
    float val = x[src] * coeff;
    float vn = __shfl_xor(val, 1);   // neighbor f^1 (same edge, same wave)
    if ((f & 1) == 0) {
        unsigned pv = __builtin_bit_cast(unsigned, __builtin_amdgcn_cvt_pkrtz(val, vn));
        pk_atomic_add(&agg1h[dst * 16 + (f >> 1)], pv);
    }
    if (f == 0) atomicAdd(&cnt1[dst], 1.0f);
}

// ---------- conv1 finish + pool1 (fused; reads f16-pair accumulator) ----------

__global__ void conv1fin_pool1(const float* __restrict__ x, const float* __restrict__ root1,
                               const float* __restrict__ bias1, const float* __restrict__ cnt1,
                               const __half2* __restrict__ agg1h, const float* __restrict__ pos,
                               const int* __restrict__ batch, const int* __restrict__ cl1,
                               unsigned* __restrict__ x1key, int* __restrict__ ccnt1,
                               float* __restrict__ pos1, int* __restrict__ batch1) {
    int gid = blockIdx.x * blockDim.x + threadIdx.x;
    if (gid >= NN * 32) return;
    int n = gid >> 5, f = gid & 31;
    __half2 hv = agg1h[n * 16 + (f >> 1)];
    float a = (f & 1) ? __high2float(hv) : __low2float(hv);
    float v = elu1(a / fmaxf(cnt1[n], 1.0f) + x[n] * root1[f] + bias1[f]);
    int c = cl1[n];
    atomicMax(&x1key[c * 32 + f], fkey(v));
    if (f == 0) {
        atomicAdd(&ccnt1[c], 1);
        atomicAdd(&pos1[c * 2], pos[n * 2]);
        atomicAdd(&pos1[c * 2 + 1], pos[n * 2 + 1]);
        atomicMax(&batch1[c], batch[n]);
    }
}

// pool1 finish: also emits x1 packed as half2 pairs for the f16 conv2
__global__ void pool1_fin(unsigned* __restrict__ x1key, const int* __restrict__ ccnt1,
                          float* __restrict__ pos1, unsigned* __restrict__ x1h) {
    int gid = blockIdx.x * blockDim.x + threadIdx.x;
    if (gid >= NP1 * 32) return;
    int c = gid >> 5, f = gid & 31;
    int cnt = ccnt1[c];
    float v = cnt > 0 ? fkey_inv(x1key[gid]) : 0.0f;
    ((float*)x1key)[gid] = v;
    float vn = __shfl_xor(v, 1);           // neighbor f^1 (adjacent lane)
    if ((f & 1) == 0)
        x1h[c * 16 + (f >> 1)] = __builtin_bit_cast(unsigned,
                                     __builtin_amdgcn_cvt_pkrtz(v, vn));
    if (f < 2) pos1[c * 2 + f] = pos1[c * 2 + f] / fmaxf((float)cnt, 1.0f);
}

// ---------- cartesian (raw cart stored; scale applied inline downstream) ----------

__global__ void cart_k(const float* __restrict__ pos1, const int* __restrict__ ei2,
                       float* __restrict__ cart, unsigned* __restrict__ scaleb) {
    int e = blockIdx.x * blockDim.x + threadIdx.x;
    float m = 0.0f;
    if (e < EE2) {
        int s = ei2[e], d = ei2[EE2 + e];
        float c0 = pos1[d * 2] - pos1[s * 2];
        float c1 = pos1[d * 2 + 1] - pos1[s * 2 + 1];
        cart[e * 2] = c0;
        cart[e * 2 + 1] = c1;
        m = fmaxf(fabsf(c0), fabsf(c1));
    }
#pragma unroll
    for (int off = 32; off > 0; off >>= 1) m = fmaxf(m, __shfl_down(m, off));
    if ((threadIdx.x & 63) == 0) atomicMax(scaleb, __float_as_uint(m));
}

// ---------- conv2: f16 weights in LDS, dot2 inner loop, packed-f16 atomics ----------

__global__ __launch_bounds__(256) void conv2_f16(const unsigned* __restrict__ x1h,
                                                 const float* __restrict__ cart,
                                                 const int* __restrict__ ei2,
                                                 const unsigned* __restrict__ scaleb,
                                                 const float* __restrict__ W2,
                                                 __half2* __restrict__ agg2h,
                                                 float* __restrict__ cnt2) {
    __shared__ unsigned wl[25 * 4 * 16 * 4];   // 6400 half2 units = 25.6KB
    const int q = blockIdx.x & 3;
    const int blk = blockIdx.x >> 2;
    const int t = threadIdx.x;

    for (int i = t; i < 6400; i += 256) {
        int pp = i & 3;
        int fh = (i >> 2) & 15;
        int gg = (i >> 6) & 3;
        int s  = i >> 8;
        int fi = gg * 8 + pp * 2;
        int fo = q * FH + fh;
        float w0 = W2[s * 2048 + fi * 64 + fo];
        float w1 = W2[s * 2048 + (fi + 1) * 64 + fo];
        wl[i] = __builtin_bit_cast(unsigned, __builtin_amdgcn_cvt_pkrtz(w0, w1));
    }
    __syncthreads();

    const float sc = fmaxf(__uint_as_float(*scaleb), 1e-12f);
    const int fh = t & (FH - 1);
    const int grp = t >> 4;
    const int EPB = (EE2 + NBLK - 1) / NBLK;
    const int e0 = blk * EPB;
    const int e_end = min(e0 + EPB, EE2);
    const uint4* wl4 = (const uint4*)wl;

    for (int e = e0 + grp; e < e_end; e += 16) {
        int src = ei2[e], dst = ei2[EE2 + e];
        float p0 = cart[2 * e] / (2.0f * sc) + 0.5f;
        float p1 = cart[2 * e + 1] / (2.0f * sc) + 0.5f;
        int idx[4]; float w[4];
        spline_basis(p0, p1, idx, w);
        const uint4* xp = (const uint4*)(x1h + src * 16);
        uint4 xq[4];
#pragma unroll
        for (int gg = 0; gg < 4; ++gg) xq[gg] = xp[gg];
        float msg = 0.0f;
#pragma unroll
        for (int k = 0; k < 4; ++k) {
            float acc = 0.0f;
#pragma unroll
            for (int gg = 0; gg < 4; ++gg) {
                uint4 wv = wl4[idx[k] * 64 + gg * 16 + fh];
                acc = dot2h(wv.x, xq[gg].x, acc);
                acc = dot2h(wv.y, xq[gg].y, acc);
                acc = dot2h(wv.z, xq[gg].z, acc);
                acc = dot2h(wv.w, xq[gg].w, acc);
            }
            msg += w[k] * acc;
        }
        float mn = __shfl_xor(msg, 1);   // neighbor fh^1 (same edge, same wave)
        if ((fh & 1) == 0) {
            unsigned pv = __builtin_bit_cast(unsigned, __builtin_amdgcn_cvt_pkrtz(msg, mn));
            pk_atomic_add(&agg2h[dst * 32 + ((q * FH + fh) >> 1)], pv);
        }
        if (q == 0 && fh == 0) atomicAdd(&cnt2[dst], 1.0f);
    }
}

// ---------- conv2 finish + pool2 (fused; reads f16-pair accumulator) ----------

__global__ void conv2fin_pool2(const float* __restrict__ x1, const float* __restrict__ root2,
                               const float* __restrict__ bias2, const float* __restrict__ cnt2,
                               const __half2* __restrict__ agg2h, const int* __restrict__ cl2,
                               const int* __restrict__ batch1, unsigned* __restrict__ x2key,
                               int* __restrict__ ccnt2, int* __restrict__ batch2) {
    int gid = blockIdx.x * blockDim.x + threadIdx.x;
    if (gid >= NP1 * 64) return;
    int n = gid >> 6, f = gid & 63;
    float r = 0.0f;
    const float* xs = x1 + n * 32;
#pragma unroll
    for (int i = 0; i < 32; ++i) r += xs[i] * root2[i * 64 + f];
    __half2 hv = agg2h[n * 32 + (f >> 1)];
    float a = (f & 1) ? __high2float(hv) : __low2float(hv);
    float v = elu1(a / fmaxf(cnt2[n], 1.0f) + r + bias2[f]);
    int c = cl2[n];
    atomicMax(&x2key[c * 64 + f], fkey(v));
    if (f == 0) {
        atomicAdd(&ccnt2[c], 1);
        atomicMax(&batch2[c], batch1[n]);
    }
}

// ---------- global mean pool: per-block LDS partials, no global atomics ----------

__global__ __launch_bounds__(256) void pool2_part(const unsigned* __restrict__ x2key,
                                                  const int* __restrict__ ccnt2,
                                                  const int* __restrict__ batch2,
                                                  float* __restrict__ partial,
                                                  float* __restrict__ pcnt) {
    __shared__ float gs[GG * 64 + GG];
    const int t = threadIdx.x;
    for (int i = t; i < GG * 64 + GG; i += 256) gs[i] = 0.0f;
    __syncthreads();
    const int lane = t & 63, wv = t >> 6;
    const int c0 = blockIdx.x * CPB2;
    const int c1 = min(c0 + CPB2, NP2);
    for (int c = c0 + wv; c < c1; c += 4) {
        int cnt = ccnt2[c];
        int g = batch2[c];
        float v = cnt > 0 ? fkey_inv(x2key[c * 64 + lane]) : 0.0f;
        atomicAdd(&gs[g * 64 + lane], v);
        if (lane == 0) atomicAdd(&gs[GG * 64 + g], 1.0f);
    }
    __syncthreads();
    float* pb = partial + (size_t)blockIdx.x * (GG * 64);
    for (int i = t; i < GG * 64; i += 256) pb[i] = gs[i];
    if (t < GG) pcnt[blockIdx.x * GG + t] = gs[GG * 64 + t];
}

// ---------- fused partial-reduce + head (one block per graph) ----------

__global__ __launch_bounds__(128) void gpool_head(const float* __restrict__ partial,
                                                  const float* __restrict__ pcnt,
                                                  const float* __restrict__ fc1w,
                                                  const float* __restrict__ fc1b,
                                                  const float* __restrict__ fc2w,
                                                  const float* __restrict__ fc2b,
                                                  float* __restrict__ out) {
    const int g = blockIdx.x;
    const int t = threadIdx.x;  // 128
    __shared__ float red[128];
    __shared__ float acc2[128];
    __shared__ float gm[64];
    __shared__ float h3[128];
    __shared__ float lg[3];

    red[t] = (t < PB2) ? pcnt[t * GG + g] : 0.0f;
    __syncthreads();
    for (int s = 64; s > 0; s >>= 1) {
        if (t < s) red[t] += red[t + s];
        __syncthreads();
    }

    const int f = t & 63, h = t >> 6;
    float acc = 0.0f;
    for (int b = h * (PB2 / 2); b < (h + 1) * (PB2 / 2); ++b)
        acc += partial[(size_t)b * (GG * 64) + g * 64 + f];
    acc2[t] = acc;
    __syncthreads();
    if (t < 64) gm[t] = (acc2[t] + acc2[t + 64]) / fmaxf(red[0], 1.0f);
    __syncthreads();

    float a = fc1b[t];
#pragma unroll
    for (int i = 0; i < 64; ++i) a += gm[i] * fc1w[i * 128 + t];
    h3[t] = elu1(a);
    __syncthreads();
    if (t < 3) {
        float a2 = fc2b[t];
#pragma unroll
        for (int i = 0; i < 128; ++i) a2 += h3[i] * fc2w[i * 3 + t];
        lg[t] = a2;
    }
    __syncthreads();
    if (t == 0) {
        float m = fmaxf(lg[0], fmaxf(lg[1], lg[2]));
        float s = expf(lg[0] - m) + expf(lg[1] - m) + expf(lg[2] - m);
        float lse = m + logf(s);
        out[g * 3 + 0] = lg[0] - lse;
        out[g * 3 + 1] = lg[1] - lse;
        out[g * 3 + 2] = lg[2] - lse;
    }
}

// ---------- launcher ----------

extern "C" void kernel_launch(void* const* d_in, const int* in_sizes, int n_in,
                              void* d_out, int out_size, void* d_ws, size_t ws_size,
                              hipStream_t stream) {
    const float* x     = (const float*)d_in[0];
    const float* pos   = (const float*)d_in[1];
    const float* eattr = (const float*)d_in[2];
    const int*   ei    = (const int*)d_in[3];
    const int*   batch = (const int*)d_in[4];
    const int*   cl1   = (const int*)d_in[5];
    const int*   ei2   = (const int*)d_in[6];
    const int*   cl2   = (const int*)d_in[7];
    const float* W1    = (const float*)d_in[8];
    const float* root1 = (const float*)d_in[9];
    const float* bias1 = (const float*)d_in[10];
    const float* W2    = (const float*)d_in[11];
    const float* root2 = (const float*)d_in[12];
    const float* bias2 = (const float*)d_in[13];
    const float* fc1w  = (const float*)d_in[14];
    const float* fc1b  = (const float*)d_in[15];
    const float* fc2w  = (const float*)d_in[16];
    const float* fc2b  = (const float*)d_in[17];
    float* out = (float*)d_out;

    char* p = (char*)d_ws;
    auto carve = [&](size_t bytes) {
        char* r = p;
        p += (bytes + 255) & ~(size_t)255;
        return r;
    };
    // regions needing zero-init first, fully-overwritten regions after the mark
    __half2*  agg1h   = (__half2*)carve((size_t)NN * 16 * 4);
    float*    cnt1    = (float*)carve((size_t)NN * 4);
    unsigned* x1key   = (unsigned*)carve((size_t)NP1 * 32 * 4);  // becomes float x1 in-place
    int*      ccnt1   = (int*)carve((size_t)NP1 * 4);
    float*    pos1    = (float*)carve((size_t)NP1 * 2 * 4);
    int*      batch1  = (int*)carve((size_t)NP1 * 4);
    unsigned* scaleb  = (unsigned*)carve(4);
    __half2*  agg2h   = (__half2*)carve((size_t)NP1 * 32 * 4);
    float*    cnt2    = (float*)carve((size_t)NP1 * 4);
    unsigned* x2key   = (unsigned*)carve((size_t)NP2 * 64 * 4);
    int*      ccnt2   = (int*)carve((size_t)NP2 * 4);
    int*      batch2  = (int*)carve((size_t)NP2 * 4);
    size_t zero_bytes = (size_t)(p - (char*)d_ws);
    unsigned* x1h     = (unsigned*)carve((size_t)NP1 * 16 * 4);  // half2-packed x1
    float*    cart    = (float*)carve((size_t)EE2 * 2 * 4);
    float*    partial = (float*)carve((size_t)PB2 * GG * 64 * 4);
    float*    pcnt    = (float*)carve((size_t)PB2 * GG * 4);

    hipMemsetAsync(d_ws, 0, zero_bytes, stream);

    const int B = 256;
    conv1_edge<<<(EE * 32 + B - 1) / B, B, 0, stream>>>(x, eattr, ei, W1, agg1h, cnt1);
    conv1fin_pool1<<<(NN * 32 + B - 1) / B, B, 0, stream>>>(x, root1, bias1, cnt1, agg1h,
                                                            pos, batch, cl1, x1key, ccnt1,
                                                            pos1, batch1);
    pool1_fin<<<(NP1 * 32 + B - 1) / B, B, 0, stream>>>(x1key, ccnt1, pos1, x1h);
    cart_k<<<(EE2 + B - 1) / B, B, 0, stream>>>(pos1, ei2, cart, scaleb);
    conv2_f16<<<NBLK * 4, B, 0, stream>>>(x1h, cart, ei2, scaleb, W2, agg2h, cnt2);
    conv2fin_pool2<<<(NP1 * 64 + B - 1) / B, B, 0, stream>>>((const float*)x1key, root2, bias2,
                                                             cnt2, agg2h, cl2, batch1, x2key,
                                                             ccnt2, batch2);
    pool2_part<<<PB2, B, 0, stream>>>(x2key, ccnt2, batch2, partial, pcnt);
    gpool_head<<<GG, 128, 0, stream>>>(partial, pcnt, fc1w, fc1b, fc2w, fc2b, out);
}